// Round 17
// baseline (614.207 us; speedup 1.0000x reference)
//
#include <hip/hip_runtime.h>
#include <hip/hip_bf16.h>
#include <math.h>

#define N_NODES 60000
#define N_EDGES 120000
#define N_BATCH 512
#define DIM 256
#define N_LAYERS 6
#define GEN_EPS 1e-7f
#define LN_EPS 1e-5f
#define NBLK ((N_NODES + 255) / 256)   // 235

typedef __attribute__((ext_vector_type(8))) short bf16x8;
typedef __attribute__((ext_vector_type(4))) float f32x4;

#define GLOBAL_AS __attribute__((address_space(1)))
#define LDS_AS __attribute__((address_space(3)))

__device__ __forceinline__ unsigned short f2bf(float f) {
    unsigned u = __float_as_uint(f);
    u = (u + 0x7fffu + ((u >> 16) & 1u)) >> 16;
    return (unsigned short)u;
}
__device__ __forceinline__ float bf2f(unsigned short u) {
    return __uint_as_float((unsigned)u << 16);
}

// ---------------- embed + LN0: h = bf16(emb[x]), y = bf16(LN(emb[x])*sc+bi) ----
__global__ void embed_ln_kernel(const int* __restrict__ x, const float* __restrict__ emb,
                                const float* __restrict__ lnsc, const float* __restrict__ lnbi,
                                unsigned short* __restrict__ h, unsigned short* __restrict__ y) {
    int row = blockIdx.x * 4 + (threadIdx.x >> 6);
    int lane = threadIdx.x & 63;
    if (row >= N_NODES) return;
    int d = lane * 4;
    int type = x[row];
    float4 v = *(const float4*)(emb + (size_t)type * DIM + d);
    ushort4 ho;
    ho.x = f2bf(v.x); ho.y = f2bf(v.y); ho.z = f2bf(v.z); ho.w = f2bf(v.w);
    *(ushort4*)(h + (size_t)row * DIM + d) = ho;
    float s = v.x + v.y + v.z + v.w;
    float q = v.x * v.x + v.y * v.y + v.z * v.z + v.w * v.w;
    #pragma unroll
    for (int off = 32; off > 0; off >>= 1) {
        s += __shfl_xor(s, off, 64);
        q += __shfl_xor(q, off, 64);
    }
    float mu = s * (1.0f / DIM);
    float var = q * (1.0f / DIM) - mu * mu;
    float r = rsqrtf(fmaxf(var, 0.0f) + LN_EPS);
    float4 sc = *(const float4*)(lnsc + d);
    float4 bi = *(const float4*)(lnbi + d);
    ushort4 o;
    o.x = f2bf((v.x - mu) * r * sc.x + bi.x);
    o.y = f2bf((v.y - mu) * r * sc.y + bi.y);
    o.z = f2bf((v.z - mu) * r * sc.z + bi.z);
    o.w = f2bf((v.w - mu) * r * sc.w + bi.w);
    *(ushort4*)(y + (size_t)row * DIM + d) = o;
}

// ---------------- CSR build ----------------
__global__ void hist_kernel(const int* __restrict__ ei, int* __restrict__ deg) {
    int e = blockIdx.x * 256 + threadIdx.x;
    if (e >= N_EDGES) return;
    atomicAdd(&deg[ei[N_EDGES + e]], 1);
}

__global__ void scan1_kernel(const int* __restrict__ deg, int* __restrict__ part) {
    __shared__ int sm[256];
    int i = blockIdx.x * 256 + threadIdx.x;
    int t = threadIdx.x;
    sm[t] = (i < N_NODES) ? deg[i] : 0;
    __syncthreads();
    for (int off = 128; off > 0; off >>= 1) {
        if (t < off) sm[t] += sm[t + off];
        __syncthreads();
    }
    if (t == 0) part[blockIdx.x] = sm[0];
}

__global__ void scan2_kernel(int* __restrict__ part) {
    __shared__ int sm[256];
    int t = threadIdx.x;
    int v = (t < NBLK) ? part[t] : 0;
    sm[t] = v;
    __syncthreads();
    for (int off = 1; off < 256; off <<= 1) {
        int add = (t >= off) ? sm[t - off] : 0;
        __syncthreads();
        sm[t] += add;
        __syncthreads();
    }
    if (t < NBLK) part[t] = sm[t] - v;   // exclusive
}

__global__ void scan3_kernel(const int* __restrict__ deg, const int* __restrict__ part,
                             int* __restrict__ ofs, int* __restrict__ cursor) {
    __shared__ int sm[256];
    int i = blockIdx.x * 256 + threadIdx.x;
    int t = threadIdx.x;
    int v = (i < N_NODES) ? deg[i] : 0;
    sm[t] = v;
    __syncthreads();
    for (int off = 1; off < 256; off <<= 1) {
        int add = (t >= off) ? sm[t - off] : 0;
        __syncthreads();
        sm[t] += add;
        __syncthreads();
    }
    int excl = part[blockIdx.x] + sm[t] - v;
    if (i < N_NODES) {
        ofs[i] = excl;
        cursor[i] = excl;
        if (i == N_NODES - 1) ofs[N_NODES] = excl + v;
    }
}

__global__ void scatter_kernel(const int* __restrict__ ei, const float* __restrict__ ea,
                               int* __restrict__ cursor, int* __restrict__ edge_src,
                               float* __restrict__ edge_a) {
    int e = blockIdx.x * 256 + threadIdx.x;
    if (e >= N_EDGES) return;
    int dst = ei[N_EDGES + e];
    int pos = atomicAdd(&cursor[dst], 1);
    edge_src[pos] = ei[e];
    edge_a[pos] = ea[e];
}

// ---------------- batch segment offsets (batch sorted) ----------------
__global__ void bofs_kernel(const int* __restrict__ batch, int* __restrict__ bofs) {
    int b = blockIdx.x * 256 + threadIdx.x;
    if (b > N_BATCH) return;
    int lo = 0, hi = N_NODES;
    while (lo < hi) {
        int mid = (lo + hi) >> 1;
        if (batch[mid] < b) lo = mid + 1; else hi = mid;
    }
    bofs[b] = lo;
}

// ---------------- gather-aggregate (reads precomputed y) -> bf16 A ----------------
__global__ void agg_kernel(const int* __restrict__ ofs, const int* __restrict__ edge_src,
                           const float* __restrict__ edge_a, const unsigned short* __restrict__ y,
                           const float* __restrict__ wlw, const float* __restrict__ wlb,
                           unsigned short* __restrict__ A) {
    const float LOG2E = 1.4426950408889634f;
    int dst = blockIdx.x * 4 + (threadIdx.x >> 6);
    int lane = threadIdx.x & 63;
    if (dst >= N_NODES) return;
    int d = lane * 4;
    float4 wv = *(const float4*)(wlw + d);
    float4 bv = *(const float4*)(wlb + d);
    int lo = ofs[dst], hi = ofs[dst + 1];
    float den0 = 0.f, den1 = 0.f, den2 = 0.f, den3 = 0.f;
    float ag0 = 0.f, ag1 = 0.f, ag2 = 0.f, ag3 = 0.f;
    for (int e = lo; e < hi; e++) {
        int src = edge_src[e];
        float a = edge_a[e];
        ushort4 u = *(const ushort4*)(y + (size_t)src * DIM + d);
        float g0 = fmaxf(bf2f(u.x) + a * wv.x + bv.x, 0.0f) + GEN_EPS;
        float g1 = fmaxf(bf2f(u.y) + a * wv.y + bv.y, 0.0f) + GEN_EPS;
        float g2 = fmaxf(bf2f(u.z) + a * wv.z + bv.z, 0.0f) + GEN_EPS;
        float g3 = fmaxf(bf2f(u.w) + a * wv.w + bv.w, 0.0f) + GEN_EPS;
        float w0 = exp2f(g0 * LOG2E), w1 = exp2f(g1 * LOG2E);
        float w2 = exp2f(g2 * LOG2E), w3 = exp2f(g3 * LOG2E);
        den0 += w0; ag0 += g0 * w0;
        den1 += w1; ag1 += g1 * w1;
        den2 += w2; ag2 += g2 * w2;
        den3 += w3; ag3 += g3 * w3;
    }
    ushort4 ud = *(const ushort4*)(y + (size_t)dst * DIM + d);
    float o0 = ag0 / fmaxf(den0, 1e-16f) + bf2f(ud.x);
    float o1 = ag1 / fmaxf(den1, 1e-16f) + bf2f(ud.y);
    float o2 = ag2 / fmaxf(den2, 1e-16f) + bf2f(ud.z);
    float o3 = ag3 / fmaxf(den3, 1e-16f) + bf2f(ud.w);
    ushort4 o;
    o.x = f2bf(o0); o.y = f2bf(o1); o.z = f2bf(o2); o.w = f2bf(o3);
    *(ushort4*)(A + (size_t)dst * DIM + d) = o;
}

// ---------------- transpose + bf16 conv weights: WT[l][n][k] = bf16(W[l][k][n]) ----
__global__ void wt_kernel(const float* __restrict__ w, unsigned short* __restrict__ wt) {
    int idx = blockIdx.x * 256 + threadIdx.x;
    if (idx >= N_LAYERS * DIM * DIM) return;
    int l = idx >> 16;
    int rem = idx & 0xFFFF;
    int n = rem >> 8;
    int k = rem & 0xFF;
    wt[idx] = f2bf(w[(size_t)l * DIM * DIM + (size_t)k * DIM + n]);
}

// LDS-tiled transpose + hi/lo split: wth/wtl[n*K+k] from w[k*N+n]; K,N % 32 == 0
__global__ __launch_bounds__(256) void wt_ro_t_kernel(const float* __restrict__ w,
                                                      unsigned short* __restrict__ wth,
                                                      unsigned short* __restrict__ wtl,
                                                      int K, int N) {
    __shared__ float tile[32][33];
    int k0 = blockIdx.x * 32, n0 = blockIdx.y * 32;
    int tx = threadIdx.x & 31, ty = threadIdx.x >> 5;   // 8 rows per pass
    #pragma unroll
    for (int i = 0; i < 4; i++)
        tile[ty + 8 * i][tx] = w[(size_t)(k0 + ty + 8 * i) * N + n0 + tx];
    __syncthreads();
    #pragma unroll
    for (int i = 0; i < 4; i++) {
        int n = ty + 8 * i;
        float v = tile[tx][n];               // w[k0+tx][n0+n]
        unsigned short hh = f2bf(v);
        size_t idx = (size_t)(n0 + n) * K + k0 + tx;
        wth[idx] = hh;
        wtl[idx] = f2bf(v - bf2f(hh));
    }
}

// ---------------- MFMA conv GEMM + fused next-layer LN ----------------
// C^T operand swap; A LDS-staged via global_load_lds; B-slice (64x256) held
// ENTIRELY in registers (32 x bf16x8 = 128 VGPR), loaded once before the loop.
// k-loop = pure ds_read + MFMA, zero global traffic.
__global__ __launch_bounds__(256) void mfma_gemm_kernel(const unsigned short* __restrict__ A,
                                                        const unsigned short* __restrict__ WT,
                                                        const float* __restrict__ bias,
                                                        const float* __restrict__ lnsc,
                                                        const float* __restrict__ lnbi,
                                                        unsigned short* __restrict__ Ch,
                                                        unsigned short* __restrict__ Cy,
                                                        int do_ln, int M) {
    __shared__ alignas(16) unsigned short Asmem[64 * 256];   // 32 KB, 512B per row
    __shared__ float lsum[64][4];
    __shared__ float lsq[64][4];
    int lane = threadIdx.x & 63;
    int w = threadIdx.x >> 6;
    int m_base = blockIdx.x * 64;
    int n_base = w * 64;
    int frow = lane & 15;
    int kp = (lane >> 4) * 8;

    // ---- stage A-tile via global_load_lds (issued first, overlaps B loads) ----
    #pragma unroll
    for (int it = 0; it < 8; it++) {
        int C = (it * 4 + w) * 64 + lane;          // chunk id, [0,2048)
        int row = C >> 5;                          // 32 chunks per 512B row
        int b0 = (C & 31) * 16;                    // dest byte-in-row
        int kb = b0 ^ ((row & 7) << 4);            // inverse-swizzled source byte
        int grow = m_base + row;
        if (grow >= M) grow = M - 1;
        const unsigned short* gsrc = A + (size_t)grow * DIM + (kb >> 1);
        unsigned short* ldst = Asmem + (size_t)(it * 4 + w) * 512;
        __builtin_amdgcn_global_load_lds((const GLOBAL_AS void*)gsrc,
                                         (LDS_AS void*)ldst, 16, 0, 0);
    }

    // ---- prefetch entire B-slice into registers (L2-hot, 32 x 16B loads) ----
    bf16x8 breg[8][4];
    #pragma unroll
    for (int s = 0; s < 8; s++)
        #pragma unroll
        for (int j = 0; j < 4; j++)
            breg[s][j] = *(const bf16x8*)(WT + (size_t)(n_base + j * 16 + frow) * DIM
                                          + s * 32 + kp);

    __syncthreads();   // drains vmcnt (A staging + B loads) + barrier

    f32x4 acc[4][4];   // acc[j][i]: C^T fragment (n-block j as rows, m-block i as cols)
    #pragma unroll
    for (int j = 0; j < 4; j++)
        #pragma unroll
        for (int i = 0; i < 4; i++) acc[j][i] = (f32x4){0.f, 0.f, 0.f, 0.f};

    #pragma unroll
    for (int s = 0; s < 8; s++) {
        bf16x8 a[4];
        #pragma unroll
        for (int i = 0; i < 4; i++) {
            int r = i * 16 + frow;
            int bb = (s * 64 + (lane >> 4) * 16) ^ ((r & 7) << 4);   // swizzled read byte
            a[i] = *(const bf16x8*)((const char*)Asmem + r * 512 + bb);
        }
        #pragma unroll
        for (int j = 0; j < 4; j++)
            #pragma unroll
            for (int i = 0; i < 4; i++)
                acc[j][i] = __builtin_amdgcn_mfma_f32_16x16x32_bf16(breg[s][j], a[i],
                                                                    acc[j][i], 0, 0, 0);
    }

    int mcol = lane & 15;          // m index within fragment
    int ng = (lane >> 4) * 4;      // n sub-offset (4 consecutive cols)

    float psum[4], psq[4];
    #pragma unroll
    for (int i = 0; i < 4; i++) { psum[i] = 0.f; psq[i] = 0.f; }

    #pragma unroll
    for (int i = 0; i < 4; i++) {
        int gm = m_base + i * 16 + mcol;
        #pragma unroll
        for (int j = 0; j < 4; j++) {
            int n0 = n_base + j * 16 + ng;
            float4 bb = *(const float4*)(bias + n0);
            float v0 = fmaxf(acc[j][i][0] + bb.x, 0.0f);
            float v1 = fmaxf(acc[j][i][1] + bb.y, 0.0f);
            float v2 = fmaxf(acc[j][i][2] + bb.z, 0.0f);
            float v3 = fmaxf(acc[j][i][3] + bb.w, 0.0f);
            acc[j][i][0] = v0; acc[j][i][1] = v1; acc[j][i][2] = v2; acc[j][i][3] = v3;
            psum[i] += v0 + v1 + v2 + v3;
            psq[i] += v0 * v0 + v1 * v1 + v2 * v2 + v3 * v3;
            if (gm < M) {
                ushort4 o;
                o.x = f2bf(v0); o.y = f2bf(v1); o.z = f2bf(v2); o.w = f2bf(v3);
                *(ushort4*)(Ch + (size_t)gm * DIM + n0) = o;
            }
        }
    }

    if (do_ln) {
        #pragma unroll
        for (int i = 0; i < 4; i++) {
            float s = psum[i], q = psq[i];
            s += __shfl_xor(s, 16, 64); q += __shfl_xor(q, 16, 64);
            s += __shfl_xor(s, 32, 64); q += __shfl_xor(q, 32, 64);
            if ((lane >> 4) == 0) {
                lsum[i * 16 + mcol][w] = s;
                lsq[i * 16 + mcol][w] = q;
            }
        }
        __syncthreads();
        #pragma unroll
        for (int i = 0; i < 4; i++) {
            int lr = i * 16 + mcol;
            float s = lsum[lr][0] + lsum[lr][1] + lsum[lr][2] + lsum[lr][3];
            float q = lsq[lr][0] + lsq[lr][1] + lsq[lr][2] + lsq[lr][3];
            float mu = s * (1.0f / DIM);
            float var = q * (1.0f / DIM) - mu * mu;
            float rs = rsqrtf(fmaxf(var, 0.0f) + LN_EPS);
            int gm = m_base + i * 16 + mcol;
            if (gm < M) {
                #pragma unroll
                for (int j = 0; j < 4; j++) {
                    int n0 = n_base + j * 16 + ng;
                    float4 sc = *(const float4*)(lnsc + n0);
                    float4 bi = *(const float4*)(lnbi + n0);
                    ushort4 o;
                    o.x = f2bf((acc[j][i][0] - mu) * rs * sc.x + bi.x);
                    o.y = f2bf((acc[j][i][1] - mu) * rs * sc.y + bi.y);
                    o.z = f2bf((acc[j][i][2] - mu) * rs * sc.z + bi.z);
                    o.w = f2bf((acc[j][i][3] - mu) * rs * sc.w + bi.w);
                    *(ushort4*)(Cy + (size_t)gm * DIM + n0) = o;
                }
            }
        }
    }
}

// ---------------- MFMA readout GEMM: block-per-16x16-tile, split-K over 4 waves ----
__global__ __launch_bounds__(256) void mfma_ro_kernel(const unsigned short* __restrict__ Ah,
                                                      const unsigned short* __restrict__ Al,
                                                      const unsigned short* __restrict__ WTh,
                                                      const unsigned short* __restrict__ WTl,
                                                      const float* __restrict__ bias,
                                                      unsigned short* __restrict__ Ch,
                                                      unsigned short* __restrict__ Cl,
                                                      int K, int Nc) {
    __shared__ float red[4][256];
    int lane = threadIdx.x & 63;
    int wave = threadIdx.x >> 6;
    int m0 = blockIdx.x * 16;
    int n0 = blockIdx.y * 16;
    int frow = lane & 15;
    int kp = (lane >> 4) * 8;
    int kc = K >> 2;                 // per-wave K chunk (384/192/96, all %32==0)
    int kbase = wave * kc;

    f32x4 acc = (f32x4){0.f, 0.f, 0.f, 0.f};
    const unsigned short* aph = Ah + (size_t)(m0 + frow) * K + kbase + kp;
    const unsigned short* apl = Al + (size_t)(m0 + frow) * K + kbase + kp;
    const unsigned short* bph = WTh + (size_t)(n0 + frow) * K + kbase + kp;
    const unsigned short* bpl = WTl + (size_t)(n0 + frow) * K + kbase + kp;
    #pragma unroll 4
    for (int k0 = 0; k0 < kc; k0 += 32) {
        bf16x8 ah = *(const bf16x8*)(aph + k0);
        bf16x8 al = *(const bf16x8*)(apl + k0);
        bf16x8 bh = *(const bf16x8*)(bph + k0);
        bf16x8 bl = *(const bf16x8*)(bpl + k0);
        acc = __builtin_amdgcn_mfma_f32_16x16x32_bf16(ah, bh, acc, 0, 0, 0);
        acc = __builtin_amdgcn_mfma_f32_16x16x32_bf16(ah, bl, acc, 0, 0, 0);
        acc = __builtin_amdgcn_mfma_f32_16x16x32_bf16(al, bh, acc, 0, 0, 0);
    }

    *(f32x4*)&red[wave][lane * 4] = acc;
    __syncthreads();
    if (wave == 0) {
        f32x4 a0 = *(const f32x4*)&red[0][lane * 4];
        f32x4 a1 = *(const f32x4*)&red[1][lane * 4];
        f32x4 a2 = *(const f32x4*)&red[2][lane * 4];
        f32x4 a3 = *(const f32x4*)&red[3][lane * 4];
        int ccol = lane & 15;
        int crow = (lane >> 4) * 4;
        float bb = bias[n0 + ccol];
        #pragma unroll
        for (int r = 0; r < 4; r++) {
            float v = a0[r] + a1[r] + a2[r] + a3[r] + bb;
            v = 0.5f * v * (1.0f + erff(v * 0.70710678118f));
            unsigned short hh = f2bf(v);
            size_t idx = (size_t)(m0 + crow + r) * Nc + n0 + ccol;
            Ch[idx] = hh;
            Cl[idx] = f2bf(v - bf2f(hh));
        }
    }
}

// ---------------- gather pooling (bf16 h) -> hi/lo bf16 outs ----------------
__global__ __launch_bounds__(256) void pool_kernel(const unsigned short* __restrict__ h,
                                                   const int* __restrict__ bofs,
                                                   unsigned short* __restrict__ outs_h,
                                                   unsigned short* __restrict__ outs_l,
                                                   int layer) {
    __shared__ float red[4][DIM];
    int b = blockIdx.x;
    int wave = threadIdx.x >> 6, lane = threadIdx.x & 63;
    int lo = bofs[b], hi = bofs[b + 1];
    float4 s = make_float4(0.f, 0.f, 0.f, 0.f);
    for (int n = lo + wave; n < hi; n += 4) {
        ushort4 u = *(const ushort4*)(h + (size_t)n * DIM + lane * 4);
        s.x += bf2f(u.x); s.y += bf2f(u.y); s.z += bf2f(u.z); s.w += bf2f(u.w);
    }
    *(float4*)(&red[wave][lane * 4]) = s;
    __syncthreads();
    int t = threadIdx.x;
    float val = red[0][t] + red[1][t] + red[2][t] + red[3][t];
    size_t idx = (size_t)b * (N_LAYERS * DIM) + layer * DIM + t;
    unsigned short hh = f2bf(val);
    outs_h[idx] = hh;
    outs_l[idx] = f2bf(val - bf2f(hh));
}

// ---------------- final: out[m] = (zh+zl)[m,:] . w3 + b3 ----------------
__global__ void final_kernel(const unsigned short* __restrict__ zh,
                             const unsigned short* __restrict__ zl,
                             const float* __restrict__ w,
                             const float* __restrict__ b, float* __restrict__ out) {
    int m = blockIdx.x * 64 + threadIdx.x;
    if (m >= N_BATCH) return;
    float s = 0.f;
    for (int k = 0; k < 192; k++)
        s += (bf2f(zh[(size_t)m * 192 + k]) + bf2f(zl[(size_t)m * 192 + k])) * w[k];
    out[m] = s + b[0];
}

__global__ void ws_sentinel_kernel(float* __restrict__ out) {
    int t = blockIdx.x * 256 + threadIdx.x;
    if (t < N_BATCH) out[t] = 1.0e6f;
}

extern "C" void kernel_launch(void* const* d_in, const int* in_sizes, int n_in,
                              void* d_out, int out_size, void* d_ws, size_t ws_size,
                              hipStream_t stream) {
    const int*   x        = (const int*)d_in[0];
    const int*   ei       = (const int*)d_in[1];
    const float* ea       = (const float*)d_in[2];
    const int*   batch    = (const int*)d_in[3];
    const float* node_emb = (const float*)d_in[4];
    const float* ln_scale = (const float*)d_in[5];
    const float* ln_bias  = (const float*)d_in[6];
    const float* wl_w     = (const float*)d_in[7];
    const float* wl_b     = (const float*)d_in[8];
    const float* conv_w   = (const float*)d_in[9];
    const float* conv_b   = (const float*)d_in[10];
    const float* ro_w0    = (const float*)d_in[11];
    const float* ro_b0    = (const float*)d_in[12];
    const float* ro_w1    = (const float*)d_in[13];
    const float* ro_b1    = (const float*)d_in[14];
    const float* ro_w2    = (const float*)d_in[15];
    const float* ro_b2    = (const float*)d_in[16];
    const float* ro_w3    = (const float*)d_in[17];
    const float* ro_b3    = (const float*)d_in[18];
    float* out = (float*)d_out;

    const size_t ND = (size_t)N_NODES * DIM;
    char* p = (char*)d_ws;
    unsigned short* hy_buf = (unsigned short*)p;  p += ND * sizeof(unsigned short);
    unsigned short* y_buf = (unsigned short*)p;   p += ND * sizeof(unsigned short);
    unsigned short* A_buf = (unsigned short*)p;   p += ND * sizeof(unsigned short);
    unsigned short* outs_h = (unsigned short*)p;  p += (size_t)N_BATCH * 1536 * sizeof(unsigned short);
    unsigned short* outs_l = (unsigned short*)p;  p += (size_t)N_BATCH * 1536 * sizeof(unsigned short);
    unsigned short* z1h = (unsigned short*)p;     p += (size_t)N_BATCH * 768 * sizeof(unsigned short);
    unsigned short* z1l = (unsigned short*)p;     p += (size_t)N_BATCH * 768 * sizeof(unsigned short);
    unsigned short* z2h = (unsigned short*)p;     p += (size_t)N_BATCH * 384 * sizeof(unsigned short);
    unsigned short* z2l = (unsigned short*)p;     p += (size_t)N_BATCH * 384 * sizeof(unsigned short);
    unsigned short* z3h = (unsigned short*)p;     p += (size_t)N_BATCH * 192 * sizeof(unsigned short);
    unsigned short* z3l = (unsigned short*)p;     p += (size_t)N_BATCH * 192 * sizeof(unsigned short);
    unsigned short* wt_buf = (unsigned short*)p;  p += (size_t)N_LAYERS * DIM * DIM * sizeof(unsigned short);
    unsigned short* wt0h = (unsigned short*)p;    p += (size_t)768 * 1536 * sizeof(unsigned short);
    unsigned short* wt0l = (unsigned short*)p;    p += (size_t)768 * 1536 * sizeof(unsigned short);
    unsigned short* wt1h = (unsigned short*)p;    p += (size_t)384 * 768 * sizeof(unsigned short);
    unsigned short* wt1l = (unsigned short*)p;    p += (size_t)384 * 768 * sizeof(unsigned short);
    unsigned short* wt2h = (unsigned short*)p;    p += (size_t)192 * 384 * sizeof(unsigned short);
    unsigned short* wt2l = (unsigned short*)p;    p += (size_t)192 * 384 * sizeof(unsigned short);
    float* edge_a = (float*)p;                    p += (size_t)N_EDGES * sizeof(float);
    int* deg = (int*)p;                           p += (size_t)N_NODES * sizeof(int);
    int* part = (int*)p;                          p += (size_t)NBLK * sizeof(int);
    int* ofs = (int*)p;                           p += (size_t)(N_NODES + 1) * sizeof(int);
    int* cursor = (int*)p;                        p += (size_t)N_NODES * sizeof(int);
    int* edge_src = (int*)p;                      p += (size_t)N_EDGES * sizeof(int);
    int* bofs = (int*)p;                          p += (size_t)(N_BATCH + 1) * sizeof(int);
    size_t need = (size_t)(p - (char*)d_ws);
    if (ws_size < need) {
        ws_sentinel_kernel<<<2, 256, 0, stream>>>(out);
        return;
    }

    int eb = (N_EDGES + 255) / 256;

    // ---- one-time prep ----
    hipMemsetAsync(deg, 0, N_NODES * sizeof(int), stream);
    hist_kernel<<<eb, 256, 0, stream>>>(ei, deg);
    scan1_kernel<<<NBLK, 256, 0, stream>>>(deg, part);
    scan2_kernel<<<1, 256, 0, stream>>>(part);
    scan3_kernel<<<NBLK, 256, 0, stream>>>(deg, part, ofs, cursor);
    scatter_kernel<<<eb, 256, 0, stream>>>(ei, ea, cursor, edge_src, edge_a);
    bofs_kernel<<<3, 256, 0, stream>>>(batch, bofs);
    wt_kernel<<<(N_LAYERS * DIM * DIM + 255) / 256, 256, 0, stream>>>(conv_w, wt_buf);
    wt_ro_t_kernel<<<dim3(1536 / 32, 768 / 32), 256, 0, stream>>>(ro_w0, wt0h, wt0l, 1536, 768);
    wt_ro_t_kernel<<<dim3(768 / 32, 384 / 32), 256, 0, stream>>>(ro_w1, wt1h, wt1l, 768, 384);
    wt_ro_t_kernel<<<dim3(384 / 32, 192 / 32), 256, 0, stream>>>(ro_w2, wt2h, wt2l, 384, 192);

    int row_blocks = (N_NODES + 3) / 4;
    int gemm_blocks = (N_NODES + 63) / 64;

    // h0 = bf16(emb[x]); y0 = LN0(h0)
    embed_ln_kernel<<<row_blocks, 256, 0, stream>>>(x, node_emb, ln_scale, ln_bias, hy_buf, y_buf);

    for (int i = 0; i < N_LAYERS; i++) {
        // A = softmax-agg(y) + y
        agg_kernel<<<row_blocks, 256, 0, stream>>>(ofs, edge_src, edge_a, y_buf,
                                                   wl_w + i * DIM, wl_b + i * DIM, A_buf);
        // h = relu(A @ Wc + bc); y = LN_{i+1}(h) fused (skip for last layer)
        int nl = (i + 1 < N_LAYERS) ? (i + 1) : i;
        mfma_gemm_kernel<<<gemm_blocks, 256, 0, stream>>>(A_buf, wt_buf + (size_t)i * DIM * DIM,
                                                          conv_b + i * DIM,
                                                          ln_scale + nl * DIM, ln_bias + nl * DIM,
                                                          hy_buf, y_buf,
                                                          (i + 1 < N_LAYERS) ? 1 : 0, N_NODES);
        pool_kernel<<<N_BATCH, 256, 0, stream>>>(hy_buf, bofs, outs_h, outs_l, i);
    }

    // readout MLP (hi/lo bf16 MFMA ~ fp32, split-K block-per-tile grids)
    mfma_ro_kernel<<<dim3(32, 48), 256, 0, stream>>>(outs_h, outs_l, wt0h, wt0l, ro_b0,
                                                     z1h, z1l, 1536, 768);
    mfma_ro_kernel<<<dim3(32, 24), 256, 0, stream>>>(z1h, z1l, wt1h, wt1l, ro_b1,
                                                     z2h, z2l, 768, 384);
    mfma_ro_kernel<<<dim3(32, 12), 256, 0, stream>>>(z2h, z2l, wt2h, wt2l, ro_b2,
                                                     z3h, z3l, 384, 192);
    final_kernel<<<(N_BATCH + 63) / 64, 64, 0, stream>>>(z3h, z3l, ro_w3, ro_b3, out);
}

// Round 18
// 553.221 us; speedup vs baseline: 1.1102x; 1.1102x over previous
//
#include <hip/hip_runtime.h>
#include <hip/hip_bf16.h>
#include <math.h>

#define N_NODES 60000
#define N_EDGES 120000
#define N_BATCH 512
#define DIM 256
#define N_LAYERS 6
#define GEN_EPS 1e-7f
#define LN_EPS 1e-5f
#define NBLK ((N_NODES + 255) / 256)   // 235

typedef __attribute__((ext_vector_type(8))) short bf16x8;
typedef __attribute__((ext_vector_type(4))) float f32x4;

#define GLOBAL_AS __attribute__((address_space(1)))
#define LDS_AS __attribute__((address_space(3)))

__device__ __forceinline__ unsigned short f2bf(float f) {
    unsigned u = __float_as_uint(f);
    u = (u + 0x7fffu + ((u >> 16) & 1u)) >> 16;
    return (unsigned short)u;
}
__device__ __forceinline__ float bf2f(unsigned short u) {
    return __uint_as_float((unsigned)u << 16);
}

// ---------------- embed + LN0: h = bf16(emb[x]), y = bf16(LN(emb[x])*sc+bi) ----
__global__ void embed_ln_kernel(const int* __restrict__ x, const float* __restrict__ emb,
                                const float* __restrict__ lnsc, const float* __restrict__ lnbi,
                                unsigned short* __restrict__ h, unsigned short* __restrict__ y) {
    int row = blockIdx.x * 4 + (threadIdx.x >> 6);
    int lane = threadIdx.x & 63;
    if (row >= N_NODES) return;
    int d = lane * 4;
    int type = x[row];
    float4 v = *(const float4*)(emb + (size_t)type * DIM + d);
    ushort4 ho;
    ho.x = f2bf(v.x); ho.y = f2bf(v.y); ho.z = f2bf(v.z); ho.w = f2bf(v.w);
    *(ushort4*)(h + (size_t)row * DIM + d) = ho;
    float s = v.x + v.y + v.z + v.w;
    float q = v.x * v.x + v.y * v.y + v.z * v.z + v.w * v.w;
    #pragma unroll
    for (int off = 32; off > 0; off >>= 1) {
        s += __shfl_xor(s, off, 64);
        q += __shfl_xor(q, off, 64);
    }
    float mu = s * (1.0f / DIM);
    float var = q * (1.0f / DIM) - mu * mu;
    float r = rsqrtf(fmaxf(var, 0.0f) + LN_EPS);
    float4 sc = *(const float4*)(lnsc + d);
    float4 bi = *(const float4*)(lnbi + d);
    ushort4 o;
    o.x = f2bf((v.x - mu) * r * sc.x + bi.x);
    o.y = f2bf((v.y - mu) * r * sc.y + bi.y);
    o.z = f2bf((v.z - mu) * r * sc.z + bi.z);
    o.w = f2bf((v.w - mu) * r * sc.w + bi.w);
    *(ushort4*)(y + (size_t)row * DIM + d) = o;
}

// ---------------- CSR build ----------------
__global__ void hist_kernel(const int* __restrict__ ei, int* __restrict__ deg) {
    int e = blockIdx.x * 256 + threadIdx.x;
    if (e >= N_EDGES) return;
    atomicAdd(&deg[ei[N_EDGES + e]], 1);
}

__global__ void scan1_kernel(const int* __restrict__ deg, int* __restrict__ part) {
    __shared__ int sm[256];
    int i = blockIdx.x * 256 + threadIdx.x;
    int t = threadIdx.x;
    sm[t] = (i < N_NODES) ? deg[i] : 0;
    __syncthreads();
    for (int off = 128; off > 0; off >>= 1) {
        if (t < off) sm[t] += sm[t + off];
        __syncthreads();
    }
    if (t == 0) part[blockIdx.x] = sm[0];
}

__global__ void scan2_kernel(int* __restrict__ part) {
    __shared__ int sm[256];
    int t = threadIdx.x;
    int v = (t < NBLK) ? part[t] : 0;
    sm[t] = v;
    __syncthreads();
    for (int off = 1; off < 256; off <<= 1) {
        int add = (t >= off) ? sm[t - off] : 0;
        __syncthreads();
        sm[t] += add;
        __syncthreads();
    }
    if (t < NBLK) part[t] = sm[t] - v;   // exclusive
}

__global__ void scan3_kernel(const int* __restrict__ deg, const int* __restrict__ part,
                             int* __restrict__ ofs, int* __restrict__ cursor) {
    __shared__ int sm[256];
    int i = blockIdx.x * 256 + threadIdx.x;
    int t = threadIdx.x;
    int v = (i < N_NODES) ? deg[i] : 0;
    sm[t] = v;
    __syncthreads();
    for (int off = 1; off < 256; off <<= 1) {
        int add = (t >= off) ? sm[t - off] : 0;
        __syncthreads();
        sm[t] += add;
        __syncthreads();
    }
    int excl = part[blockIdx.x] + sm[t] - v;
    if (i < N_NODES) {
        ofs[i] = excl;
        cursor[i] = excl;
        if (i == N_NODES - 1) ofs[N_NODES] = excl + v;
    }
}

__global__ void scatter_kernel(const int* __restrict__ ei, const float* __restrict__ ea,
                               int* __restrict__ cursor, int* __restrict__ edge_src,
                               float* __restrict__ edge_a) {
    int e = blockIdx.x * 256 + threadIdx.x;
    if (e >= N_EDGES) return;
    int dst = ei[N_EDGES + e];
    int pos = atomicAdd(&cursor[dst], 1);
    edge_src[pos] = ei[e];
    edge_a[pos] = ea[e];
}

// ---------------- batch segment offsets (batch sorted) ----------------
__global__ void bofs_kernel(const int* __restrict__ batch, int* __restrict__ bofs) {
    int b = blockIdx.x * 256 + threadIdx.x;
    if (b > N_BATCH) return;
    int lo = 0, hi = N_NODES;
    while (lo < hi) {
        int mid = (lo + hi) >> 1;
        if (batch[mid] < b) lo = mid + 1; else hi = mid;
    }
    bofs[b] = lo;
}

// ---------------- gather-aggregate (2-edge unrolled ILP) -> bf16 A ----------------
__global__ void agg_kernel(const int* __restrict__ ofs, const int* __restrict__ edge_src,
                           const float* __restrict__ edge_a, const unsigned short* __restrict__ y,
                           const float* __restrict__ wlw, const float* __restrict__ wlb,
                           unsigned short* __restrict__ A) {
    const float LOG2E = 1.4426950408889634f;
    int dst = blockIdx.x * 4 + (threadIdx.x >> 6);
    int lane = threadIdx.x & 63;
    if (dst >= N_NODES) return;
    int d = lane * 4;
    float4 wv = *(const float4*)(wlw + d);
    float4 bv = *(const float4*)(wlb + d);
    int lo = ofs[dst], hi = ofs[dst + 1];
    float den0 = 0.f, den1 = 0.f, den2 = 0.f, den3 = 0.f;
    float ag0 = 0.f, ag1 = 0.f, ag2 = 0.f, ag3 = 0.f;
    int e = lo;
    for (; e + 1 < hi; e += 2) {
        int s0 = edge_src[e];
        int s1 = edge_src[e + 1];
        float a0 = edge_a[e];
        float a1 = edge_a[e + 1];
        ushort4 u0 = *(const ushort4*)(y + (size_t)s0 * DIM + d);
        ushort4 u1 = *(const ushort4*)(y + (size_t)s1 * DIM + d);
        float g0 = fmaxf(bf2f(u0.x) + a0 * wv.x + bv.x, 0.0f) + GEN_EPS;
        float g1 = fmaxf(bf2f(u0.y) + a0 * wv.y + bv.y, 0.0f) + GEN_EPS;
        float g2 = fmaxf(bf2f(u0.z) + a0 * wv.z + bv.z, 0.0f) + GEN_EPS;
        float g3 = fmaxf(bf2f(u0.w) + a0 * wv.w + bv.w, 0.0f) + GEN_EPS;
        float h0 = fmaxf(bf2f(u1.x) + a1 * wv.x + bv.x, 0.0f) + GEN_EPS;
        float h1 = fmaxf(bf2f(u1.y) + a1 * wv.y + bv.y, 0.0f) + GEN_EPS;
        float h2 = fmaxf(bf2f(u1.z) + a1 * wv.z + bv.z, 0.0f) + GEN_EPS;
        float h3 = fmaxf(bf2f(u1.w) + a1 * wv.w + bv.w, 0.0f) + GEN_EPS;
        float w0 = exp2f(g0 * LOG2E), w1 = exp2f(g1 * LOG2E);
        float w2 = exp2f(g2 * LOG2E), w3 = exp2f(g3 * LOG2E);
        float x0 = exp2f(h0 * LOG2E), x1 = exp2f(h1 * LOG2E);
        float x2 = exp2f(h2 * LOG2E), x3 = exp2f(h3 * LOG2E);
        den0 += w0 + x0; ag0 += g0 * w0 + h0 * x0;
        den1 += w1 + x1; ag1 += g1 * w1 + h1 * x1;
        den2 += w2 + x2; ag2 += g2 * w2 + h2 * x2;
        den3 += w3 + x3; ag3 += g3 * w3 + h3 * x3;
    }
    if (e < hi) {
        int src = edge_src[e];
        float a = edge_a[e];
        ushort4 u = *(const ushort4*)(y + (size_t)src * DIM + d);
        float g0 = fmaxf(bf2f(u.x) + a * wv.x + bv.x, 0.0f) + GEN_EPS;
        float g1 = fmaxf(bf2f(u.y) + a * wv.y + bv.y, 0.0f) + GEN_EPS;
        float g2 = fmaxf(bf2f(u.z) + a * wv.z + bv.z, 0.0f) + GEN_EPS;
        float g3 = fmaxf(bf2f(u.w) + a * wv.w + bv.w, 0.0f) + GEN_EPS;
        float w0 = exp2f(g0 * LOG2E), w1 = exp2f(g1 * LOG2E);
        float w2 = exp2f(g2 * LOG2E), w3 = exp2f(g3 * LOG2E);
        den0 += w0; ag0 += g0 * w0;
        den1 += w1; ag1 += g1 * w1;
        den2 += w2; ag2 += g2 * w2;
        den3 += w3; ag3 += g3 * w3;
    }
    ushort4 ud = *(const ushort4*)(y + (size_t)dst * DIM + d);
    float o0 = ag0 / fmaxf(den0, 1e-16f) + bf2f(ud.x);
    float o1 = ag1 / fmaxf(den1, 1e-16f) + bf2f(ud.y);
    float o2 = ag2 / fmaxf(den2, 1e-16f) + bf2f(ud.z);
    float o3 = ag3 / fmaxf(den3, 1e-16f) + bf2f(ud.w);
    ushort4 o;
    o.x = f2bf(o0); o.y = f2bf(o1); o.z = f2bf(o2); o.w = f2bf(o3);
    *(ushort4*)(A + (size_t)dst * DIM + d) = o;
}

// ---------------- transpose + bf16 conv weights: WT[l][n][k] = bf16(W[l][k][n]) ----
__global__ void wt_kernel(const float* __restrict__ w, unsigned short* __restrict__ wt) {
    int idx = blockIdx.x * 256 + threadIdx.x;
    if (idx >= N_LAYERS * DIM * DIM) return;
    int l = idx >> 16;
    int rem = idx & 0xFFFF;
    int n = rem >> 8;
    int k = rem & 0xFF;
    wt[idx] = f2bf(w[(size_t)l * DIM * DIM + (size_t)k * DIM + n]);
}

// LDS-tiled transpose + hi/lo split: wth/wtl[n*K+k] from w[k*N+n]; K,N % 32 == 0
__global__ __launch_bounds__(256) void wt_ro_t_kernel(const float* __restrict__ w,
                                                      unsigned short* __restrict__ wth,
                                                      unsigned short* __restrict__ wtl,
                                                      int K, int N) {
    __shared__ float tile[32][33];
    int k0 = blockIdx.x * 32, n0 = blockIdx.y * 32;
    int tx = threadIdx.x & 31, ty = threadIdx.x >> 5;   // 8 rows per pass
    #pragma unroll
    for (int i = 0; i < 4; i++)
        tile[ty + 8 * i][tx] = w[(size_t)(k0 + ty + 8 * i) * N + n0 + tx];
    __syncthreads();
    #pragma unroll
    for (int i = 0; i < 4; i++) {
        int n = ty + 8 * i;
        float v = tile[tx][n];               // w[k0+tx][n0+n]
        unsigned short hh = f2bf(v);
        size_t idx = (size_t)(n0 + n) * K + k0 + tx;
        wth[idx] = hh;
        wtl[idx] = f2bf(v - bf2f(hh));
    }
}

// ---------------- MFMA conv GEMM + fused next-layer LN (R17 structure) ----------
__global__ __launch_bounds__(256) void mfma_gemm_kernel(const unsigned short* __restrict__ A,
                                                        const unsigned short* __restrict__ WT,
                                                        const float* __restrict__ bias,
                                                        const float* __restrict__ lnsc,
                                                        const float* __restrict__ lnbi,
                                                        unsigned short* __restrict__ Ch,
                                                        unsigned short* __restrict__ Cy,
                                                        int do_ln, int M) {
    __shared__ alignas(16) unsigned short Asmem[64 * 256];   // 32 KB, 512B per row
    __shared__ float lsum[64][4];
    __shared__ float lsq[64][4];
    int lane = threadIdx.x & 63;
    int w = threadIdx.x >> 6;
    int m_base = blockIdx.x * 64;
    int n_base = w * 64;
    int frow = lane & 15;
    int kp = (lane >> 4) * 8;

    #pragma unroll
    for (int it = 0; it < 8; it++) {
        int C = (it * 4 + w) * 64 + lane;
        int row = C >> 5;
        int b0 = (C & 31) * 16;
        int kb = b0 ^ ((row & 7) << 4);
        int grow = m_base + row;
        if (grow >= M) grow = M - 1;
        const unsigned short* gsrc = A + (size_t)grow * DIM + (kb >> 1);
        unsigned short* ldst = Asmem + (size_t)(it * 4 + w) * 512;
        __builtin_amdgcn_global_load_lds((const GLOBAL_AS void*)gsrc,
                                         (LDS_AS void*)ldst, 16, 0, 0);
    }

    bf16x8 breg[8][4];
    #pragma unroll
    for (int s = 0; s < 8; s++)
        #pragma unroll
        for (int j = 0; j < 4; j++)
            breg[s][j] = *(const bf16x8*)(WT + (size_t)(n_base + j * 16 + frow) * DIM
                                          + s * 32 + kp);

    __syncthreads();

    f32x4 acc[4][4];
    #pragma unroll
    for (int j = 0; j < 4; j++)
        #pragma unroll
        for (int i = 0; i < 4; i++) acc[j][i] = (f32x4){0.f, 0.f, 0.f, 0.f};

    #pragma unroll
    for (int s = 0; s < 8; s++) {
        bf16x8 a[4];
        #pragma unroll
        for (int i = 0; i < 4; i++) {
            int r = i * 16 + frow;
            int bb = (s * 64 + (lane >> 4) * 16) ^ ((r & 7) << 4);
            a[i] = *(const bf16x8*)((const char*)Asmem + r * 512 + bb);
        }
        #pragma unroll
        for (int j = 0; j < 4; j++)
            #pragma unroll
            for (int i = 0; i < 4; i++)
                acc[j][i] = __builtin_amdgcn_mfma_f32_16x16x32_bf16(breg[s][j], a[i],
                                                                    acc[j][i], 0, 0, 0);
    }

    int mcol = lane & 15;
    int ng = (lane >> 4) * 4;

    float psum[4], psq[4];
    #pragma unroll
    for (int i = 0; i < 4; i++) { psum[i] = 0.f; psq[i] = 0.f; }

    #pragma unroll
    for (int i = 0; i < 4; i++) {
        int gm = m_base + i * 16 + mcol;
        #pragma unroll
        for (int j = 0; j < 4; j++) {
            int n0 = n_base + j * 16 + ng;
            float4 bb = *(const float4*)(bias + n0);
            float v0 = fmaxf(acc[j][i][0] + bb.x, 0.0f);
            float v1 = fmaxf(acc[j][i][1] + bb.y, 0.0f);
            float v2 = fmaxf(acc[j][i][2] + bb.z, 0.0f);
            float v3 = fmaxf(acc[j][i][3] + bb.w, 0.0f);
            acc[j][i][0] = v0; acc[j][i][1] = v1; acc[j][i][2] = v2; acc[j][i][3] = v3;
            psum[i] += v0 + v1 + v2 + v3;
            psq[i] += v0 * v0 + v1 * v1 + v2 * v2 + v3 * v3;
            if (gm < M) {
                ushort4 o;
                o.x = f2bf(v0); o.y = f2bf(v1); o.z = f2bf(v2); o.w = f2bf(v3);
                *(ushort4*)(Ch + (size_t)gm * DIM + n0) = o;
            }
        }
    }

    if (do_ln) {
        #pragma unroll
        for (int i = 0; i < 4; i++) {
            float s = psum[i], q = psq[i];
            s += __shfl_xor(s, 16, 64); q += __shfl_xor(q, 16, 64);
            s += __shfl_xor(s, 32, 64); q += __shfl_xor(q, 32, 64);
            if ((lane >> 4) == 0) {
                lsum[i * 16 + mcol][w] = s;
                lsq[i * 16 + mcol][w] = q;
            }
        }
        __syncthreads();
        #pragma unroll
        for (int i = 0; i < 4; i++) {
            int lr = i * 16 + mcol;
            float s = lsum[lr][0] + lsum[lr][1] + lsum[lr][2] + lsum[lr][3];
            float q = lsq[lr][0] + lsq[lr][1] + lsq[lr][2] + lsq[lr][3];
            float mu = s * (1.0f / DIM);
            float var = q * (1.0f / DIM) - mu * mu;
            float rs = rsqrtf(fmaxf(var, 0.0f) + LN_EPS);
            int gm = m_base + i * 16 + mcol;
            if (gm < M) {
                #pragma unroll
                for (int j = 0; j < 4; j++) {
                    int n0 = n_base + j * 16 + ng;
                    float4 sc = *(const float4*)(lnsc + n0);
                    float4 bi = *(const float4*)(lnbi + n0);
                    ushort4 o;
                    o.x = f2bf((acc[j][i][0] - mu) * rs * sc.x + bi.x);
                    o.y = f2bf((acc[j][i][1] - mu) * rs * sc.y + bi.y);
                    o.z = f2bf((acc[j][i][2] - mu) * rs * sc.z + bi.z);
                    o.w = f2bf((acc[j][i][3] - mu) * rs * sc.w + bi.w);
                    *(ushort4*)(Cy + (size_t)gm * DIM + n0) = o;
                }
            }
        }
    }
}

// ---------------- MFMA readout GEMM: block-per-16x16-tile, split-K over 4 waves ----
__global__ __launch_bounds__(256) void mfma_ro_kernel(const unsigned short* __restrict__ Ah,
                                                      const unsigned short* __restrict__ Al,
                                                      const unsigned short* __restrict__ WTh,
                                                      const unsigned short* __restrict__ WTl,
                                                      const float* __restrict__ bias,
                                                      unsigned short* __restrict__ Ch,
                                                      unsigned short* __restrict__ Cl,
                                                      int K, int Nc) {
    __shared__ float red[4][256];
    int lane = threadIdx.x & 63;
    int wave = threadIdx.x >> 6;
    int m0 = blockIdx.x * 16;
    int n0 = blockIdx.y * 16;
    int frow = lane & 15;
    int kp = (lane >> 4) * 8;
    int kc = K >> 2;
    int kbase = wave * kc;

    f32x4 acc = (f32x4){0.f, 0.f, 0.f, 0.f};
    const unsigned short* aph = Ah + (size_t)(m0 + frow) * K + kbase + kp;
    const unsigned short* apl = Al + (size_t)(m0 + frow) * K + kbase + kp;
    const unsigned short* bph = WTh + (size_t)(n0 + frow) * K + kbase + kp;
    const unsigned short* bpl = WTl + (size_t)(n0 + frow) * K + kbase + kp;
    #pragma unroll 4
    for (int k0 = 0; k0 < kc; k0 += 32) {
        bf16x8 ah = *(const bf16x8*)(aph + k0);
        bf16x8 al = *(const bf16x8*)(apl + k0);
        bf16x8 bh = *(const bf16x8*)(bph + k0);
        bf16x8 bl = *(const bf16x8*)(bpl + k0);
        acc = __builtin_amdgcn_mfma_f32_16x16x32_bf16(ah, bh, acc, 0, 0, 0);
        acc = __builtin_amdgcn_mfma_f32_16x16x32_bf16(ah, bl, acc, 0, 0, 0);
        acc = __builtin_amdgcn_mfma_f32_16x16x32_bf16(al, bh, acc, 0, 0, 0);
    }

    *(f32x4*)&red[wave][lane * 4] = acc;
    __syncthreads();
    if (wave == 0) {
        f32x4 a0 = *(const f32x4*)&red[0][lane * 4];
        f32x4 a1 = *(const f32x4*)&red[1][lane * 4];
        f32x4 a2 = *(const f32x4*)&red[2][lane * 4];
        f32x4 a3 = *(const f32x4*)&red[3][lane * 4];
        int ccol = lane & 15;
        int crow = (lane >> 4) * 4;
        float bb = bias[n0 + ccol];
        #pragma unroll
        for (int r = 0; r < 4; r++) {
            float v = a0[r] + a1[r] + a2[r] + a3[r] + bb;
            v = 0.5f * v * (1.0f + erff(v * 0.70710678118f));
            unsigned short hh = f2bf(v);
            size_t idx = (size_t)(m0 + crow + r) * Nc + n0 + ccol;
            Ch[idx] = hh;
            Cl[idx] = f2bf(v - bf2f(hh));
        }
    }
}

// ---------------- gather pooling: grid (B, 4 col-blocks), 16 row-ways ----------
__global__ __launch_bounds__(256) void pool_kernel(const unsigned short* __restrict__ h,
                                                   const int* __restrict__ bofs,
                                                   unsigned short* __restrict__ outs_h,
                                                   unsigned short* __restrict__ outs_l,
                                                   int layer) {
    __shared__ float red[16][68];   // padded stride breaks bank conflicts
    int b = blockIdx.x;
    int cb = blockIdx.y;                 // column block: cols cb*64..+63
    int way = threadIdx.x >> 4;          // 0..15 row-ways
    int li = threadIdx.x & 15;           // 16 lanes x ushort4 = 64 cols
    int col = cb * 64 + li * 4;
    int lo = bofs[b], hi = bofs[b + 1];
    float4 s = make_float4(0.f, 0.f, 0.f, 0.f);
    for (int n = lo + way; n < hi; n += 16) {
        ushort4 u = *(const ushort4*)(h + (size_t)n * DIM + col);
        s.x += bf2f(u.x); s.y += bf2f(u.y); s.z += bf2f(u.z); s.w += bf2f(u.w);
    }
    *(float4*)(&red[way][li * 4]) = s;
    __syncthreads();
    if (threadIdx.x < 64) {
        int t = threadIdx.x;
        float val = 0.f;
        #pragma unroll
        for (int k = 0; k < 16; k++) val += red[k][t];
        size_t idx = (size_t)b * (N_LAYERS * DIM) + layer * DIM + cb * 64 + t;
        unsigned short hh = f2bf(val);
        outs_h[idx] = hh;
        outs_l[idx] = f2bf(val - bf2f(hh));
    }
}

// ---------------- final: out[m] = (zh+zl)[m,:] . w3 + b3 ----------------
__global__ void final_kernel(const unsigned short* __restrict__ zh,
                             const unsigned short* __restrict__ zl,
                             const float* __restrict__ w,
                             const float* __restrict__ b, float* __restrict__ out) {
    int m = blockIdx.x * 64 + threadIdx.x;
    if (m >= N_BATCH) return;
    float s = 0.f;
    for (int k = 0; k < 192; k++)
        s += (bf2f(zh[(size_t)m * 192 + k]) + bf2f(zl[(size_t)m * 192 + k])) * w[k];
    out[m] = s + b[0];
}

__global__ void ws_sentinel_kernel(float* __restrict__ out) {
    int t = blockIdx.x * 256 + threadIdx.x;
    if (t < N_BATCH) out[t] = 1.0e6f;
}

extern "C" void kernel_launch(void* const* d_in, const int* in_sizes, int n_in,
                              void* d_out, int out_size, void* d_ws, size_t ws_size,
                              hipStream_t stream) {
    const int*   x        = (const int*)d_in[0];
    const int*   ei       = (const int*)d_in[1];
    const float* ea       = (const float*)d_in[2];
    const int*   batch    = (const int*)d_in[3];
    const float* node_emb = (const float*)d_in[4];
    const float* ln_scale = (const float*)d_in[5];
    const float* ln_bias  = (const float*)d_in[6];
    const float* wl_w     = (const float*)d_in[7];
    const float* wl_b     = (const float*)d_in[8];
    const float* conv_w   = (const float*)d_in[9];
    const float* conv_b   = (const float*)d_in[10];
    const float* ro_w0    = (const float*)d_in[11];
    const float* ro_b0    = (const float*)d_in[12];
    const float* ro_w1    = (const float*)d_in[13];
    const float* ro_b1    = (const float*)d_in[14];
    const float* ro_w2    = (const float*)d_in[15];
    const float* ro_b2    = (const float*)d_in[16];
    const float* ro_w3    = (const float*)d_in[17];
    const float* ro_b3    = (const float*)d_in[18];
    float* out = (float*)d_out;

    const size_t ND = (size_t)N_NODES * DIM;
    char* p = (char*)d_ws;
    unsigned short* hy_buf = (unsigned short*)p;  p += ND * sizeof(unsigned short);
    unsigned short* y_buf = (unsigned short*)p;   p += ND * sizeof(unsigned short);
    unsigned short* A_buf = (unsigned short*)p;   p += ND * sizeof(unsigned short);
    unsigned short* outs_h = (unsigned short*)p;  p += (size_t)N_BATCH * 1536 * sizeof(unsigned short);
    unsigned short* outs_l = (unsigned short*)p;  p += (size_t)N_BATCH * 1536 * sizeof(unsigned short);
    unsigned short* z1h = (unsigned short*)p;     p += (size_t)N_BATCH * 768 * sizeof(unsigned short);
    unsigned short* z1l = (unsigned short*)p;     p += (size_t)N_BATCH * 768 * sizeof(unsigned short);
    unsigned short* z2h = (unsigned short*)p;     p += (size_t)N_BATCH * 384 * sizeof(unsigned short);
    unsigned short* z2l = (unsigned short*)p;     p += (size_t)N_BATCH * 384 * sizeof(unsigned short);
    unsigned short* z3h = (unsigned short*)p;     p += (size_t)N_BATCH * 192 * sizeof(unsigned short);
    unsigned short* z3l = (unsigned short*)p;     p += (size_t)N_BATCH * 192 * sizeof(unsigned short);
    unsigned short* wt_buf = (unsigned short*)p;  p += (size_t)N_LAYERS * DIM * DIM * sizeof(unsigned short);
    unsigned short* wt0h = (unsigned short*)p;    p += (size_t)768 * 1536 * sizeof(unsigned short);
    unsigned short* wt0l = (unsigned short*)p;    p += (size_t)768 * 1536 * sizeof(unsigned short);
    unsigned short* wt1h = (unsigned short*)p;    p += (size_t)384 * 768 * sizeof(unsigned short);
    unsigned short* wt1l = (unsigned short*)p;    p += (size_t)384 * 768 * sizeof(unsigned short);
    unsigned short* wt2h = (unsigned short*)p;    p += (size_t)192 * 384 * sizeof(unsigned short);
    unsigned short* wt2l = (unsigned short*)p;    p += (size_t)192 * 384 * sizeof(unsigned short);
    float* edge_a = (float*)p;                    p += (size_t)N_EDGES * sizeof(float);
    int* deg = (int*)p;                           p += (size_t)N_NODES * sizeof(int);
    int* part = (int*)p;                          p += (size_t)NBLK * sizeof(int);
    int* ofs = (int*)p;                           p += (size_t)(N_NODES + 1) * sizeof(int);
    int* cursor = (int*)p;                        p += (size_t)N_NODES * sizeof(int);
    int* edge_src = (int*)p;                      p += (size_t)N_EDGES * sizeof(int);
    int* bofs = (int*)p;                          p += (size_t)(N_BATCH + 1) * sizeof(int);
    size_t need = (size_t)(p - (char*)d_ws);
    if (ws_size < need) {
        ws_sentinel_kernel<<<2, 256, 0, stream>>>(out);
        return;
    }

    int eb = (N_EDGES + 255) / 256;

    // ---- one-time prep ----
    hipMemsetAsync(deg, 0, N_NODES * sizeof(int), stream);
    hist_kernel<<<eb, 256, 0, stream>>>(ei, deg);
    scan1_kernel<<<NBLK, 256, 0, stream>>>(deg, part);
    scan2_kernel<<<1, 256, 0, stream>>>(part);
    scan3_kernel<<<NBLK, 256, 0, stream>>>(deg, part, ofs, cursor);
    scatter_kernel<<<eb, 256, 0, stream>>>(ei, ea, cursor, edge_src, edge_a);
    bofs_kernel<<<3, 256, 0, stream>>>(batch, bofs);
    wt_kernel<<<(N_LAYERS * DIM * DIM + 255) / 256, 256, 0, stream>>>(conv_w, wt_buf);
    wt_ro_t_kernel<<<dim3(1536 / 32, 768 / 32), 256, 0, stream>>>(ro_w0, wt0h, wt0l, 1536, 768);
    wt_ro_t_kernel<<<dim3(768 / 32, 384 / 32), 256, 0, stream>>>(ro_w1, wt1h, wt1l, 768, 384);
    wt_ro_t_kernel<<<dim3(384 / 32, 192 / 32), 256, 0, stream>>>(ro_w2, wt2h, wt2l, 384, 192);

    int row_blocks = (N_NODES + 3) / 4;
    int gemm_blocks = (N_NODES + 63) / 64;

    // h0 = bf16(emb[x]); y0 = LN0(h0)
    embed_ln_kernel<<<row_blocks, 256, 0, stream>>>(x, node_emb, ln_scale, ln_bias, hy_buf, y_buf);

    for (int i = 0; i < N_LAYERS; i++) {
        agg_kernel<<<row_blocks, 256, 0, stream>>>(ofs, edge_src, edge_a, y_buf,
                                                   wl_w + i * DIM, wl_b + i * DIM, A_buf);
        int nl = (i + 1 < N_LAYERS) ? (i + 1) : i;
        mfma_gemm_kernel<<<gemm_blocks, 256, 0, stream>>>(A_buf, wt_buf + (size_t)i * DIM * DIM,
                                                          conv_b + i * DIM,
                                                          ln_scale + nl * DIM, ln_bias + nl * DIM,
                                                          hy_buf, y_buf,
                                                          (i + 1 < N_LAYERS) ? 1 : 0, N_NODES);
        pool_kernel<<<dim3(N_BATCH, 4), 256, 0, stream>>>(hy_buf, bofs, outs_h, outs_l, i);
    }

    // readout MLP (hi/lo bf16 MFMA ~ fp32, split-K block-per-tile grids)
    mfma_ro_kernel<<<dim3(32, 48), 256, 0, stream>>>(outs_h, outs_l, wt0h, wt0l, ro_b0,
                                                     z1h, z1l, 1536, 768);
    mfma_ro_kernel<<<dim3(32, 24), 256, 0, stream>>>(z1h, z1l, wt1h, wt1l, ro_b1,
                                                     z2h, z2l, 768, 384);
    mfma_ro_kernel<<<dim3(32, 12), 256, 0, stream>>>(z2h, z2l, wt2h, wt2l, ro_b2,
                                                     z3h, z3l, 384, 192);
    final_kernel<<<(N_BATCH + 63) / 64, 64, 0, stream>>>(z3h, z3l, ro_w3, ro_b3, out);
}

// Round 19
// 547.653 us; speedup vs baseline: 1.1215x; 1.0102x over previous
//
#include <hip/hip_runtime.h>
#include <hip/hip_bf16.h>
#include <math.h>

#define N_NODES 60000
#define N_EDGES 120000
#define N_BATCH 512
#define DIM 256
#define N_LAYERS 6
#define GEN_EPS 1e-7f
#define LN_EPS 1e-5f
#define NBLK ((N_NODES + 255) / 256)   // 235

typedef __attribute__((ext_vector_type(8))) short bf16x8;
typedef __attribute__((ext_vector_type(4))) float f32x4;

#define GLOBAL_AS __attribute__((address_space(1)))
#define LDS_AS __attribute__((address_space(3)))

__device__ __forceinline__ unsigned short f2bf(float f) {
    unsigned u = __float_as_uint(f);
    u = (u + 0x7fffu + ((u >> 16) & 1u)) >> 16;
    return (unsigned short)u;
}
__device__ __forceinline__ float bf2f(unsigned short u) {
    return __uint_as_float((unsigned)u << 16);
}

// ---------------- embed + LN0: y = bf16(LN(emb[x])*sc+bi)  (h never stored) ----
__global__ void embed_ln_kernel(const int* __restrict__ x, const float* __restrict__ emb,
                                const float* __restrict__ lnsc, const float* __restrict__ lnbi,
                                unsigned short* __restrict__ y) {
    int row = blockIdx.x * 4 + (threadIdx.x >> 6);
    int lane = threadIdx.x & 63;
    if (row >= N_NODES) return;
    int d = lane * 4;
    int type = x[row];
    float4 v = *(const float4*)(emb + (size_t)type * DIM + d);
    float s = v.x + v.y + v.z + v.w;
    float q = v.x * v.x + v.y * v.y + v.z * v.z + v.w * v.w;
    #pragma unroll
    for (int off = 32; off > 0; off >>= 1) {
        s += __shfl_xor(s, off, 64);
        q += __shfl_xor(q, off, 64);
    }
    float mu = s * (1.0f / DIM);
    float var = q * (1.0f / DIM) - mu * mu;
    float r = rsqrtf(fmaxf(var, 0.0f) + LN_EPS);
    float4 sc = *(const float4*)(lnsc + d);
    float4 bi = *(const float4*)(lnbi + d);
    ushort4 o;
    o.x = f2bf((v.x - mu) * r * sc.x + bi.x);
    o.y = f2bf((v.y - mu) * r * sc.y + bi.y);
    o.z = f2bf((v.z - mu) * r * sc.z + bi.z);
    o.w = f2bf((v.w - mu) * r * sc.w + bi.w);
    *(ushort4*)(y + (size_t)row * DIM + d) = o;
}

// ---------------- CSR build ----------------
__global__ void hist_kernel(const int* __restrict__ ei, int* __restrict__ deg) {
    int e = blockIdx.x * 256 + threadIdx.x;
    if (e >= N_EDGES) return;
    atomicAdd(&deg[ei[N_EDGES + e]], 1);
}

__global__ void scan1_kernel(const int* __restrict__ deg, int* __restrict__ part) {
    __shared__ int sm[256];
    int i = blockIdx.x * 256 + threadIdx.x;
    int t = threadIdx.x;
    sm[t] = (i < N_NODES) ? deg[i] : 0;
    __syncthreads();
    for (int off = 128; off > 0; off >>= 1) {
        if (t < off) sm[t] += sm[t + off];
        __syncthreads();
    }
    if (t == 0) part[blockIdx.x] = sm[0];
}

__global__ void scan2_kernel(int* __restrict__ part) {
    __shared__ int sm[256];
    int t = threadIdx.x;
    int v = (t < NBLK) ? part[t] : 0;
    sm[t] = v;
    __syncthreads();
    for (int off = 1; off < 256; off <<= 1) {
        int add = (t >= off) ? sm[t - off] : 0;
        __syncthreads();
        sm[t] += add;
        __syncthreads();
    }
    if (t < NBLK) part[t] = sm[t] - v;   // exclusive
}

__global__ void scan3_kernel(const int* __restrict__ deg, const int* __restrict__ part,
                             int* __restrict__ ofs, int* __restrict__ cursor) {
    __shared__ int sm[256];
    int i = blockIdx.x * 256 + threadIdx.x;
    int t = threadIdx.x;
    int v = (i < N_NODES) ? deg[i] : 0;
    sm[t] = v;
    __syncthreads();
    for (int off = 1; off < 256; off <<= 1) {
        int add = (t >= off) ? sm[t - off] : 0;
        __syncthreads();
        sm[t] += add;
        __syncthreads();
    }
    int excl = part[blockIdx.x] + sm[t] - v;
    if (i < N_NODES) {
        ofs[i] = excl;
        cursor[i] = excl;
        if (i == N_NODES - 1) ofs[N_NODES] = excl + v;
    }
}

__global__ void scatter_kernel(const int* __restrict__ ei, const float* __restrict__ ea,
                               int* __restrict__ cursor, int* __restrict__ edge_src,
                               float* __restrict__ edge_a) {
    int e = blockIdx.x * 256 + threadIdx.x;
    if (e >= N_EDGES) return;
    int dst = ei[N_EDGES + e];
    int pos = atomicAdd(&cursor[dst], 1);
    edge_src[pos] = ei[e];
    edge_a[pos] = ea[e];
}

// ---------------- gather-aggregate (2-edge unrolled ILP) -> bf16 A ----------------
__global__ void agg_kernel(const int* __restrict__ ofs, const int* __restrict__ edge_src,
                           const float* __restrict__ edge_a, const unsigned short* __restrict__ y,
                           const float* __restrict__ wlw, const float* __restrict__ wlb,
                           unsigned short* __restrict__ A) {
    const float LOG2E = 1.4426950408889634f;
    int dst = blockIdx.x * 4 + (threadIdx.x >> 6);
    int lane = threadIdx.x & 63;
    if (dst >= N_NODES) return;
    int d = lane * 4;
    float4 wv = *(const float4*)(wlw + d);
    float4 bv = *(const float4*)(wlb + d);
    int lo = ofs[dst], hi = ofs[dst + 1];
    float den0 = 0.f, den1 = 0.f, den2 = 0.f, den3 = 0.f;
    float ag0 = 0.f, ag1 = 0.f, ag2 = 0.f, ag3 = 0.f;
    int e = lo;
    for (; e + 1 < hi; e += 2) {
        int s0 = edge_src[e];
        int s1 = edge_src[e + 1];
        float a0 = edge_a[e];
        float a1 = edge_a[e + 1];
        ushort4 u0 = *(const ushort4*)(y + (size_t)s0 * DIM + d);
        ushort4 u1 = *(const ushort4*)(y + (size_t)s1 * DIM + d);
        float g0 = fmaxf(bf2f(u0.x) + a0 * wv.x + bv.x, 0.0f) + GEN_EPS;
        float g1 = fmaxf(bf2f(u0.y) + a0 * wv.y + bv.y, 0.0f) + GEN_EPS;
        float g2 = fmaxf(bf2f(u0.z) + a0 * wv.z + bv.z, 0.0f) + GEN_EPS;
        float g3 = fmaxf(bf2f(u0.w) + a0 * wv.w + bv.w, 0.0f) + GEN_EPS;
        float h0 = fmaxf(bf2f(u1.x) + a1 * wv.x + bv.x, 0.0f) + GEN_EPS;
        float h1 = fmaxf(bf2f(u1.y) + a1 * wv.y + bv.y, 0.0f) + GEN_EPS;
        float h2 = fmaxf(bf2f(u1.z) + a1 * wv.z + bv.z, 0.0f) + GEN_EPS;
        float h3 = fmaxf(bf2f(u1.w) + a1 * wv.w + bv.w, 0.0f) + GEN_EPS;
        float w0 = exp2f(g0 * LOG2E), w1 = exp2f(g1 * LOG2E);
        float w2 = exp2f(g2 * LOG2E), w3 = exp2f(g3 * LOG2E);
        float x0 = exp2f(h0 * LOG2E), x1 = exp2f(h1 * LOG2E);
        float x2 = exp2f(h2 * LOG2E), x3 = exp2f(h3 * LOG2E);
        den0 += w0 + x0; ag0 += g0 * w0 + h0 * x0;
        den1 += w1 + x1; ag1 += g1 * w1 + h1 * x1;
        den2 += w2 + x2; ag2 += g2 * w2 + h2 * x2;
        den3 += w3 + x3; ag3 += g3 * w3 + h3 * x3;
    }
    if (e < hi) {
        int src = edge_src[e];
        float a = edge_a[e];
        ushort4 u = *(const ushort4*)(y + (size_t)src * DIM + d);
        float g0 = fmaxf(bf2f(u.x) + a * wv.x + bv.x, 0.0f) + GEN_EPS;
        float g1 = fmaxf(bf2f(u.y) + a * wv.y + bv.y, 0.0f) + GEN_EPS;
        float g2 = fmaxf(bf2f(u.z) + a * wv.z + bv.z, 0.0f) + GEN_EPS;
        float g3 = fmaxf(bf2f(u.w) + a * wv.w + bv.w, 0.0f) + GEN_EPS;
        float w0 = exp2f(g0 * LOG2E), w1 = exp2f(g1 * LOG2E);
        float w2 = exp2f(g2 * LOG2E), w3 = exp2f(g3 * LOG2E);
        den0 += w0; ag0 += g0 * w0;
        den1 += w1; ag1 += g1 * w1;
        den2 += w2; ag2 += g2 * w2;
        den3 += w3; ag3 += g3 * w3;
    }
    ushort4 ud = *(const ushort4*)(y + (size_t)dst * DIM + d);
    float o0 = ag0 / fmaxf(den0, 1e-16f) + bf2f(ud.x);
    float o1 = ag1 / fmaxf(den1, 1e-16f) + bf2f(ud.y);
    float o2 = ag2 / fmaxf(den2, 1e-16f) + bf2f(ud.z);
    float o3 = ag3 / fmaxf(den3, 1e-16f) + bf2f(ud.w);
    ushort4 o;
    o.x = f2bf(o0); o.y = f2bf(o1); o.z = f2bf(o2); o.w = f2bf(o3);
    *(ushort4*)(A + (size_t)dst * DIM + d) = o;
}

// ---------------- transpose + bf16 conv weights: WT[l][n][k] = bf16(W[l][k][n]) ----
__global__ void wt_kernel(const float* __restrict__ w, unsigned short* __restrict__ wt) {
    int idx = blockIdx.x * 256 + threadIdx.x;
    if (idx >= N_LAYERS * DIM * DIM) return;
    int l = idx >> 16;
    int rem = idx & 0xFFFF;
    int n = rem >> 8;
    int k = rem & 0xFF;
    wt[idx] = f2bf(w[(size_t)l * DIM * DIM + (size_t)k * DIM + n]);
}

// LDS-tiled transpose + hi/lo split: wth/wtl[n*K+k] from w[k*N+n]; K,N % 32 == 0
__global__ __launch_bounds__(256) void wt_ro_t_kernel(const float* __restrict__ w,
                                                      unsigned short* __restrict__ wth,
                                                      unsigned short* __restrict__ wtl,
                                                      int K, int N) {
    __shared__ float tile[32][33];
    int k0 = blockIdx.x * 32, n0 = blockIdx.y * 32;
    int tx = threadIdx.x & 31, ty = threadIdx.x >> 5;   // 8 rows per pass
    #pragma unroll
    for (int i = 0; i < 4; i++)
        tile[ty + 8 * i][tx] = w[(size_t)(k0 + ty + 8 * i) * N + n0 + tx];
    __syncthreads();
    #pragma unroll
    for (int i = 0; i < 4; i++) {
        int n = ty + 8 * i;
        float v = tile[tx][n];               // w[k0+tx][n0+n]
        unsigned short hh = f2bf(v);
        size_t idx = (size_t)(n0 + n) * K + k0 + tx;
        wth[idx] = hh;
        wtl[idx] = f2bf(v - bf2f(hh));
    }
}

// ---------------- MFMA conv GEMM + fused LN + FUSED POOLING ----------------
// C^T swap, LDS-staged A. h never materialized: pool via batch_lds + shuffle
// reduce + fp32 atomics into outs_f32; y = LN(h) stored for next layer.
__global__ __launch_bounds__(256) void mfma_gemm_kernel(const unsigned short* __restrict__ A,
                                                        const unsigned short* __restrict__ WT,
                                                        const float* __restrict__ bias,
                                                        const float* __restrict__ lnsc,
                                                        const float* __restrict__ lnbi,
                                                        const int* __restrict__ batch,
                                                        float* __restrict__ outs_f32,
                                                        int layer,
                                                        unsigned short* __restrict__ Cy,
                                                        int do_ln, int M) {
    __shared__ alignas(16) unsigned short Asmem[64 * 256];   // 32 KB, 512B per row
    __shared__ float lsum[64][4];
    __shared__ float lsq[64][4];
    __shared__ int batch_lds[64];
    int lane = threadIdx.x & 63;
    int w = threadIdx.x >> 6;
    int m_base = blockIdx.x * 64;
    int n_base = w * 64;
    int frow = lane & 15;
    int kp = (lane >> 4) * 8;

    #pragma unroll
    for (int it = 0; it < 8; it++) {
        int C = (it * 4 + w) * 64 + lane;
        int row = C >> 5;
        int b0 = (C & 31) * 16;
        int kb = b0 ^ ((row & 7) << 4);
        int grow = m_base + row;
        if (grow >= M) grow = M - 1;
        const unsigned short* gsrc = A + (size_t)grow * DIM + (kb >> 1);
        unsigned short* ldst = Asmem + (size_t)(it * 4 + w) * 512;
        __builtin_amdgcn_global_load_lds((const GLOBAL_AS void*)gsrc,
                                         (LDS_AS void*)ldst, 16, 0, 0);
    }
    if (threadIdx.x < 64) {
        int gm = m_base + threadIdx.x;
        batch_lds[threadIdx.x] = batch[gm < M ? gm : (M - 1)];
    }

    __syncthreads();

    f32x4 acc[4][4];
    #pragma unroll
    for (int j = 0; j < 4; j++)
        #pragma unroll
        for (int i = 0; i < 4; i++) acc[j][i] = (f32x4){0.f, 0.f, 0.f, 0.f};

    #pragma unroll
    for (int s = 0; s < 8; s++) {
        bf16x8 a[4], b[4];
        #pragma unroll
        for (int i = 0; i < 4; i++) {
            int r = i * 16 + frow;
            int bb = (s * 64 + (lane >> 4) * 16) ^ ((r & 7) << 4);
            a[i] = *(const bf16x8*)((const char*)Asmem + r * 512 + bb);
        }
        #pragma unroll
        for (int j = 0; j < 4; j++)
            b[j] = *(const bf16x8*)(WT + (size_t)(n_base + j * 16 + frow) * DIM + s * 32 + kp);
        #pragma unroll
        for (int j = 0; j < 4; j++)
            #pragma unroll
            for (int i = 0; i < 4; i++)
                acc[j][i] = __builtin_amdgcn_mfma_f32_16x16x32_bf16(b[j], a[i],
                                                                    acc[j][i], 0, 0, 0);
    }

    int mcol = lane & 15;          // m index within fragment
    int ng = (lane >> 4) * 4;      // n sub-offset (4 consecutive cols)

    float psum[4], psq[4];
    #pragma unroll
    for (int i = 0; i < 4; i++) { psum[i] = 0.f; psq[i] = 0.f; }

    // v = relu(acc + bias) kept in acc; LN row partials
    #pragma unroll
    for (int i = 0; i < 4; i++) {
        #pragma unroll
        for (int j = 0; j < 4; j++) {
            int n0 = n_base + j * 16 + ng;
            float4 bb = *(const float4*)(bias + n0);
            float v0 = fmaxf(acc[j][i][0] + bb.x, 0.0f);
            float v1 = fmaxf(acc[j][i][1] + bb.y, 0.0f);
            float v2 = fmaxf(acc[j][i][2] + bb.z, 0.0f);
            float v3 = fmaxf(acc[j][i][3] + bb.w, 0.0f);
            acc[j][i][0] = v0; acc[j][i][1] = v1; acc[j][i][2] = v2; acc[j][i][3] = v3;
            psum[i] += v0 + v1 + v2 + v3;
            psq[i] += v0 * v0 + v1 * v1 + v2 * v2 + v3 * v3;
        }
    }

    // ---- fused pooling: outs_f32[seg, layer*256 + col] += sum over rows ----
    float* outbase = outs_f32 + (size_t)layer * DIM;
    if (batch_lds[0] == batch_lds[63]) {
        // whole block in one segment: sum over i in-register, reduce over 16 row-lanes
        int seg = batch_lds[0];
        #pragma unroll
        for (int j = 0; j < 4; j++) {
            float t0 = 0.f, t1 = 0.f, t2 = 0.f, t3 = 0.f;
            #pragma unroll
            for (int i = 0; i < 4; i++) {
                int gm = m_base + i * 16 + mcol;
                if (gm < M) {
                    t0 += acc[j][i][0]; t1 += acc[j][i][1];
                    t2 += acc[j][i][2]; t3 += acc[j][i][3];
                }
            }
            #pragma unroll
            for (int off = 1; off < 16; off <<= 1) {
                t0 += __shfl_xor(t0, off, 64);
                t1 += __shfl_xor(t1, off, 64);
                t2 += __shfl_xor(t2, off, 64);
                t3 += __shfl_xor(t3, off, 64);
            }
            if (mcol == 0) {
                float* op = outbase + (size_t)seg * (N_LAYERS * DIM) + n_base + j * 16 + ng;
                atomicAdd(op + 0, t0); atomicAdd(op + 1, t1);
                atomicAdd(op + 2, t2); atomicAdd(op + 3, t3);
            }
        }
    } else {
        // general: per i-group, loop over contiguous segment range (batch sorted)
        #pragma unroll
        for (int i = 0; i < 4; i++) {
            int segA = batch_lds[i * 16];
            int segB = batch_lds[i * 16 + 15];
            int myseg = batch_lds[i * 16 + mcol];
            int gm = m_base + i * 16 + mcol;
            for (int seg = segA; seg <= segB; seg++) {
                bool mine = (myseg == seg) && (gm < M);
                #pragma unroll
                for (int j = 0; j < 4; j++) {
                    float t0 = mine ? acc[j][i][0] : 0.f;
                    float t1 = mine ? acc[j][i][1] : 0.f;
                    float t2 = mine ? acc[j][i][2] : 0.f;
                    float t3 = mine ? acc[j][i][3] : 0.f;
                    #pragma unroll
                    for (int off = 1; off < 16; off <<= 1) {
                        t0 += __shfl_xor(t0, off, 64);
                        t1 += __shfl_xor(t1, off, 64);
                        t2 += __shfl_xor(t2, off, 64);
                        t3 += __shfl_xor(t3, off, 64);
                    }
                    if (mcol == 0) {
                        float* op = outbase + (size_t)seg * (N_LAYERS * DIM) + n_base + j * 16 + ng;
                        atomicAdd(op + 0, t0); atomicAdd(op + 1, t1);
                        atomicAdd(op + 2, t2); atomicAdd(op + 3, t3);
                    }
                }
            }
        }
    }

    if (do_ln) {
        #pragma unroll
        for (int i = 0; i < 4; i++) {
            float s = psum[i], q = psq[i];
            s += __shfl_xor(s, 16, 64); q += __shfl_xor(q, 16, 64);
            s += __shfl_xor(s, 32, 64); q += __shfl_xor(q, 32, 64);
            if ((lane >> 4) == 0) {
                lsum[i * 16 + mcol][w] = s;
                lsq[i * 16 + mcol][w] = q;
            }
        }
        __syncthreads();
        #pragma unroll
        for (int i = 0; i < 4; i++) {
            int lr = i * 16 + mcol;
            float s = lsum[lr][0] + lsum[lr][1] + lsum[lr][2] + lsum[lr][3];
            float q = lsq[lr][0] + lsq[lr][1] + lsq[lr][2] + lsq[lr][3];
            float mu = s * (1.0f / DIM);
            float var = q * (1.0f / DIM) - mu * mu;
            float rs = rsqrtf(fmaxf(var, 0.0f) + LN_EPS);
            int gm = m_base + i * 16 + mcol;
            if (gm < M) {
                #pragma unroll
                for (int j = 0; j < 4; j++) {
                    int n0 = n_base + j * 16 + ng;
                    float4 sc = *(const float4*)(lnsc + n0);
                    float4 bi = *(const float4*)(lnbi + n0);
                    ushort4 o;
                    o.x = f2bf((acc[j][i][0] - mu) * rs * sc.x + bi.x);
                    o.y = f2bf((acc[j][i][1] - mu) * rs * sc.y + bi.y);
                    o.z = f2bf((acc[j][i][2] - mu) * rs * sc.z + bi.z);
                    o.w = f2bf((acc[j][i][3] - mu) * rs * sc.w + bi.w);
                    *(ushort4*)(Cy + (size_t)gm * DIM + n0) = o;
                }
            }
        }
    }
}

// ---------------- fp32 outs -> hi/lo bf16 ----------------
__global__ void conv_outs_kernel(const float* __restrict__ outs_f32,
                                 unsigned short* __restrict__ oh,
                                 unsigned short* __restrict__ ol) {
    int idx = blockIdx.x * 256 + threadIdx.x;
    if (idx >= N_BATCH * N_LAYERS * DIM) return;
    float v = outs_f32[idx];
    unsigned short hh = f2bf(v);
    oh[idx] = hh;
    ol[idx] = f2bf(v - bf2f(hh));
}

// ---------------- MFMA readout GEMM: block-per-16x16-tile, split-K over 4 waves ----
__global__ __launch_bounds__(256) void mfma_ro_kernel(const unsigned short* __restrict__ Ah,
                                                      const unsigned short* __restrict__ Al,
                                                      const unsigned short* __restrict__ WTh,
                                                      const unsigned short* __restrict__ WTl,
                                                      const float* __restrict__ bias,
                                                      unsigned short* __restrict__ Ch,
                                                      unsigned short* __restrict__ Cl,
                                                      int K, int Nc) {
    __shared__ float red[4][256];
    int lane = threadIdx.x & 63;
    int wave = threadIdx.x >> 6;
    int m0 = blockIdx.x * 16;
    int n0 = blockIdx.y * 16;
    int frow = lane & 15;
    int kp = (lane >> 4) * 8;
    int kc = K >> 2;
    int kbase = wave * kc;

    f32x4 acc = (f32x4){0.f, 0.f, 0.f, 0.f};
    const unsigned short* aph = Ah + (size_t)(m0 + frow) * K + kbase + kp;
    const unsigned short* apl = Al + (size_t)(m0 + frow) * K + kbase + kp;
    const unsigned short* bph = WTh + (size_t)(n0 + frow) * K + kbase + kp;
    const unsigned short* bpl = WTl + (size_t)(n0 + frow) * K + kbase + kp;
    #pragma unroll 4
    for (int k0 = 0; k0 < kc; k0 += 32) {
        bf16x8 ah = *(const bf16x8*)(aph + k0);
        bf16x8 al = *(const bf16x8*)(apl + k0);
        bf16x8 bh = *(const bf16x8*)(bph + k0);
        bf16x8 bl = *(const bf16x8*)(bpl + k0);
        acc = __builtin_amdgcn_mfma_f32_16x16x32_bf16(ah, bh, acc, 0, 0, 0);
        acc = __builtin_amdgcn_mfma_f32_16x16x32_bf16(ah, bl, acc, 0, 0, 0);
        acc = __builtin_amdgcn_mfma_f32_16x16x32_bf16(al, bh, acc, 0, 0, 0);
    }

    *(f32x4*)&red[wave][lane * 4] = acc;
    __syncthreads();
    if (wave == 0) {
        f32x4 a0 = *(const f32x4*)&red[0][lane * 4];
        f32x4 a1 = *(const f32x4*)&red[1][lane * 4];
        f32x4 a2 = *(const f32x4*)&red[2][lane * 4];
        f32x4 a3 = *(const f32x4*)&red[3][lane * 4];
        int ccol = lane & 15;
        int crow = (lane >> 4) * 4;
        float bb = bias[n0 + ccol];
        #pragma unroll
        for (int r = 0; r < 4; r++) {
            float v = a0[r] + a1[r] + a2[r] + a3[r] + bb;
            v = 0.5f * v * (1.0f + erff(v * 0.70710678118f));
            unsigned short hh = f2bf(v);
            size_t idx = (size_t)(m0 + crow + r) * Nc + n0 + ccol;
            Ch[idx] = hh;
            Cl[idx] = f2bf(v - bf2f(hh));
        }
    }
}

// ---------------- final: out[m] = (zh+zl)[m,:] . w3 + b3 ----------------
__global__ void final_kernel(const unsigned short* __restrict__ zh,
                             const unsigned short* __restrict__ zl,
                             const float* __restrict__ w,
                             const float* __restrict__ b, float* __restrict__ out) {
    int m = blockIdx.x * 64 + threadIdx.x;
    if (m >= N_BATCH) return;
    float s = 0.f;
    for (int k = 0; k < 192; k++)
        s += (bf2f(zh[(size_t)m * 192 + k]) + bf2f(zl[(size_t)m * 192 + k])) * w[k];
    out[m] = s + b[0];
}

__global__ void ws_sentinel_kernel(float* __restrict__ out) {
    int t = blockIdx.x * 256 + threadIdx.x;
    if (t < N_BATCH) out[t] = 1.0e6f;
}

extern "C" void kernel_launch(void* const* d_in, const int* in_sizes, int n_in,
                              void* d_out, int out_size, void* d_ws, size_t ws_size,
                              hipStream_t stream) {
    const int*   x        = (const int*)d_in[0];
    const int*   ei       = (const int*)d_in[1];
    const float* ea       = (const float*)d_in[2];
    const int*   batch    = (const int*)d_in[3];
    const float* node_emb = (const float*)d_in[4];
    const float* ln_scale = (const float*)d_in[5];
    const float* ln_bias  = (const float*)d_in[6];
    const float* wl_w     = (const float*)d_in[7];
    const float* wl_b     = (const float*)d_in[8];
    const float* conv_w   = (const float*)d_in[9];
    const float* conv_b   = (const float*)d_in[10];
    const float* ro_w0    = (const float*)d_in[11];
    const float* ro_b0    = (const float*)d_in[12];
    const float* ro_w1    = (const float*)d_in[13];
    const float* ro_b1    = (const float*)d_in[14];
    const float* ro_w2    = (const float*)d_in[15];
    const float* ro_b2    = (const float*)d_in[16];
    const float* ro_w3    = (const float*)d_in[17];
    const float* ro_b3    = (const float*)d_in[18];
    float* out = (float*)d_out;

    const size_t ND = (size_t)N_NODES * DIM;
    char* p = (char*)d_ws;
    unsigned short* y_buf = (unsigned short*)p;   p += ND * sizeof(unsigned short);
    unsigned short* A_buf = (unsigned short*)p;   p += ND * sizeof(unsigned short);
    float* outs_f32 = (float*)p;                  p += (size_t)N_BATCH * 1536 * sizeof(float);
    unsigned short* outs_h = (unsigned short*)p;  p += (size_t)N_BATCH * 1536 * sizeof(unsigned short);
    unsigned short* outs_l = (unsigned short*)p;  p += (size_t)N_BATCH * 1536 * sizeof(unsigned short);
    unsigned short* z1h = (unsigned short*)p;     p += (size_t)N_BATCH * 768 * sizeof(unsigned short);
    unsigned short* z1l = (unsigned short*)p;     p += (size_t)N_BATCH * 768 * sizeof(unsigned short);
    unsigned short* z2h = (unsigned short*)p;     p += (size_t)N_BATCH * 384 * sizeof(unsigned short);
    unsigned short* z2l = (unsigned short*)p;     p += (size_t)N_BATCH * 384 * sizeof(unsigned short);
    unsigned short* z3h = (unsigned short*)p;     p += (size_t)N_BATCH * 192 * sizeof(unsigned short);
    unsigned short* z3l = (unsigned short*)p;     p += (size_t)N_BATCH * 192 * sizeof(unsigned short);
    unsigned short* wt_buf = (unsigned short*)p;  p += (size_t)N_LAYERS * DIM * DIM * sizeof(unsigned short);
    unsigned short* wt0h = (unsigned short*)p;    p += (size_t)768 * 1536 * sizeof(unsigned short);
    unsigned short* wt0l = (unsigned short*)p;    p += (size_t)768 * 1536 * sizeof(unsigned short);
    unsigned short* wt1h = (unsigned short*)p;    p += (size_t)384 * 768 * sizeof(unsigned short);
    unsigned short* wt1l = (unsigned short*)p;    p += (size_t)384 * 768 * sizeof(unsigned short);
    unsigned short* wt2h = (unsigned short*)p;    p += (size_t)192 * 384 * sizeof(unsigned short);
    unsigned short* wt2l = (unsigned short*)p;    p += (size_t)192 * 384 * sizeof(unsigned short);
    float* edge_a = (float*)p;                    p += (size_t)N_EDGES * sizeof(float);
    int* deg = (int*)p;                           p += (size_t)N_NODES * sizeof(int);
    int* part = (int*)p;                          p += (size_t)NBLK * sizeof(int);
    int* ofs = (int*)p;                           p += (size_t)(N_NODES + 1) * sizeof(int);
    int* cursor = (int*)p;                        p += (size_t)N_NODES * sizeof(int);
    int* edge_src = (int*)p;                      p += (size_t)N_EDGES * sizeof(int);
    size_t need = (size_t)(p - (char*)d_ws);
    if (ws_size < need) {
        ws_sentinel_kernel<<<2, 256, 0, stream>>>(out);
        return;
    }

    int eb = (N_EDGES + 255) / 256;

    // ---- one-time prep ----
    hipMemsetAsync(deg, 0, N_NODES * sizeof(int), stream);
    hipMemsetAsync(outs_f32, 0, (size_t)N_BATCH * 1536 * sizeof(float), stream);
    hist_kernel<<<eb, 256, 0, stream>>>(ei, deg);
    scan1_kernel<<<NBLK, 256, 0, stream>>>(deg, part);
    scan2_kernel<<<1, 256, 0, stream>>>(part);
    scan3_kernel<<<NBLK, 256, 0, stream>>>(deg, part, ofs, cursor);
    scatter_kernel<<<eb, 256, 0, stream>>>(ei, ea, cursor, edge_src, edge_a);
    wt_kernel<<<(N_LAYERS * DIM * DIM + 255) / 256, 256, 0, stream>>>(conv_w, wt_buf);
    wt_ro_t_kernel<<<dim3(1536 / 32, 768 / 32), 256, 0, stream>>>(ro_w0, wt0h, wt0l, 1536, 768);
    wt_ro_t_kernel<<<dim3(768 / 32, 384 / 32), 256, 0, stream>>>(ro_w1, wt1h, wt1l, 768, 384);
    wt_ro_t_kernel<<<dim3(384 / 32, 192 / 32), 256, 0, stream>>>(ro_w2, wt2h, wt2l, 384, 192);

    int row_blocks = (N_NODES + 3) / 4;
    int gemm_blocks = (N_NODES + 63) / 64;

    // y0 = LN0(emb[x])  (h never materialized)
    embed_ln_kernel<<<row_blocks, 256, 0, stream>>>(x, node_emb, ln_scale, ln_bias, y_buf);

    for (int i = 0; i < N_LAYERS; i++) {
        agg_kernel<<<row_blocks, 256, 0, stream>>>(ofs, edge_src, edge_a, y_buf,
                                                   wl_w + i * DIM, wl_b + i * DIM, A_buf);
        int nl = (i + 1 < N_LAYERS) ? (i + 1) : i;
        mfma_gemm_kernel<<<gemm_blocks, 256, 0, stream>>>(A_buf, wt_buf + (size_t)i * DIM * DIM,
                                                          conv_b + i * DIM,
                                                          ln_scale + nl * DIM, ln_bias + nl * DIM,
                                                          batch, outs_f32, i, y_buf,
                                                          (i + 1 < N_LAYERS) ? 1 : 0, N_NODES);
    }

    // outs fp32 -> hi/lo bf16
    conv_outs_kernel<<<(N_BATCH * 1536 + 255) / 256, 256, 0, stream>>>(outs_f32, outs_h, outs_l);

    // readout MLP (hi/lo bf16 MFMA ~ fp32, split-K block-per-tile grids)
    mfma_ro_kernel<<<dim3(32, 48), 256, 0, stream>>>(outs_h, outs_l, wt0h, wt0l, ro_b0,
                                                     z1h, z1l, 1536, 768);
    mfma_ro_kernel<<<dim3(32, 24), 256, 0, stream>>>(z1h, z1l, wt1h, wt1l, ro_b1,
                                                     z2h, z2l, 768, 384);
    mfma_ro_kernel<<<dim3(32, 12), 256, 0, stream>>>(z2h, z2l, wt2h, wt2l, ro_b2,
                                                     z3h, z3l, 384, 192);
    final_kernel<<<(N_BATCH + 63) / 64, 64, 0, stream>>>(z3h, z3l, ro_w3, ro_b3, out);
}

// Round 21
// 507.849 us; speedup vs baseline: 1.2094x; 1.0784x over previous
//
#include <hip/hip_runtime.h>
#include <hip/hip_bf16.h>
#include <math.h>

#define N_NODES 60000
#define N_EDGES 120000
#define N_BATCH 512
#define DIM 256
#define N_LAYERS 6
#define GEN_EPS 1e-7f
#define LN_EPS 1e-5f
#define NBLK ((N_NODES + 255) / 256)   // 235

typedef __attribute__((ext_vector_type(8))) short bf16x8;
typedef __attribute__((ext_vector_type(4))) float f32x4;

#define GLOBAL_AS __attribute__((address_space(1)))
#define LDS_AS __attribute__((address_space(3)))

__device__ __forceinline__ unsigned short f2bf(float f) {
    unsigned u = __float_as_uint(f);
    u = (u + 0x7fffu + ((u >> 16) & 1u)) >> 16;
    return (unsigned short)u;
}
__device__ __forceinline__ float bf2f(unsigned short u) {
    return __uint_as_float((unsigned)u << 16);
}

// ---------------- embed + LN0: y = bf16(LN(emb[x])*sc+bi)  (h never stored) ----
__global__ void embed_ln_kernel(const int* __restrict__ x, const float* __restrict__ emb,
                                const float* __restrict__ lnsc, const float* __restrict__ lnbi,
                                unsigned short* __restrict__ y) {
    int row = blockIdx.x * 4 + (threadIdx.x >> 6);
    int lane = threadIdx.x & 63;
    if (row >= N_NODES) return;
    int d = lane * 4;
    int type = x[row];
    float4 v = *(const float4*)(emb + (size_t)type * DIM + d);
    float s = v.x + v.y + v.z + v.w;
    float q = v.x * v.x + v.y * v.y + v.z * v.z + v.w * v.w;
    #pragma unroll
    for (int off = 32; off > 0; off >>= 1) {
        s += __shfl_xor(s, off, 64);
        q += __shfl_xor(q, off, 64);
    }
    float mu = s * (1.0f / DIM);
    float var = q * (1.0f / DIM) - mu * mu;
    float r = rsqrtf(fmaxf(var, 0.0f) + LN_EPS);
    float4 sc = *(const float4*)(lnsc + d);
    float4 bi = *(const float4*)(lnbi + d);
    ushort4 o;
    o.x = f2bf((v.x - mu) * r * sc.x + bi.x);
    o.y = f2bf((v.y - mu) * r * sc.y + bi.y);
    o.z = f2bf((v.z - mu) * r * sc.z + bi.z);
    o.w = f2bf((v.w - mu) * r * sc.w + bi.w);
    *(ushort4*)(y + (size_t)row * DIM + d) = o;
}

// ---------------- CSR build ----------------
__global__ void hist_kernel(const int* __restrict__ ei, int* __restrict__ deg) {
    int e = blockIdx.x * 256 + threadIdx.x;
    if (e >= N_EDGES) return;
    atomicAdd(&deg[ei[N_EDGES + e]], 1);
}

__global__ void scan1_kernel(const int* __restrict__ deg, int* __restrict__ part) {
    __shared__ int sm[256];
    int i = blockIdx.x * 256 + threadIdx.x;
    int t = threadIdx.x;
    sm[t] = (i < N_NODES) ? deg[i] : 0;
    __syncthreads();
    for (int off = 128; off > 0; off >>= 1) {
        if (t < off) sm[t] += sm[t + off];
        __syncthreads();
    }
    if (t == 0) part[blockIdx.x] = sm[0];
}

__global__ void scan2_kernel(int* __restrict__ part) {
    __shared__ int sm[256];
    int t = threadIdx.x;
    int v = (t < NBLK) ? part[t] : 0;
    sm[t] = v;
    __syncthreads();
    for (int off = 1; off < 256; off <<= 1) {
        int add = (t >= off) ? sm[t - off] : 0;
        __syncthreads();
        sm[t] += add;
        __syncthreads();
    }
    if (t < NBLK) part[t] = sm[t] - v;   // exclusive
}

__global__ void scan3_kernel(const int* __restrict__ deg, const int* __restrict__ part,
                             int* __restrict__ ofs, int* __restrict__ cursor) {
    __shared__ int sm[256];
    int i = blockIdx.x * 256 + threadIdx.x;
    int t = threadIdx.x;
    int v = (i < N_NODES) ? deg[i] : 0;
    sm[t] = v;
    __syncthreads();
    for (int off = 1; off < 256; off <<= 1) {
        int add = (t >= off) ? sm[t - off] : 0;
        __syncthreads();
        sm[t] += add;
        __syncthreads();
    }
    int excl = part[blockIdx.x] + sm[t] - v;
    if (i < N_NODES) {
        ofs[i] = excl;
        cursor[i] = excl;
        if (i == N_NODES - 1) ofs[N_NODES] = excl + v;
    }
}

__global__ void scatter_kernel(const int* __restrict__ ei, const float* __restrict__ ea,
                               int* __restrict__ cursor, int* __restrict__ edge_src,
                               float* __restrict__ edge_a) {
    int e = blockIdx.x * 256 + threadIdx.x;
    if (e >= N_EDGES) return;
    int dst = ei[N_EDGES + e];
    int pos = atomicAdd(&cursor[dst], 1);
    edge_src[pos] = ei[e];
    edge_a[pos] = ea[e];
}

// ---------------- gather-aggregate (2-edge unrolled ILP) -> bf16 A ----------------
__global__ void agg_kernel(const int* __restrict__ ofs, const int* __restrict__ edge_src,
                           const float* __restrict__ edge_a, const unsigned short* __restrict__ y,
                           const float* __restrict__ wlw, const float* __restrict__ wlb,
                           unsigned short* __restrict__ A) {
    const float LOG2E = 1.4426950408889634f;
    int dst = blockIdx.x * 4 + (threadIdx.x >> 6);
    int lane = threadIdx.x & 63;
    if (dst >= N_NODES) return;
    int d = lane * 4;
    float4 wv = *(const float4*)(wlw + d);
    float4 bv = *(const float4*)(wlb + d);
    int lo = ofs[dst], hi = ofs[dst + 1];
    float den0 = 0.f, den1 = 0.f, den2 = 0.f, den3 = 0.f;
    float ag0 = 0.f, ag1 = 0.f, ag2 = 0.f, ag3 = 0.f;
    int e = lo;
    for (; e + 1 < hi; e += 2) {
        int s0 = edge_src[e];
        int s1 = edge_src[e + 1];
        float a0 = edge_a[e];
        float a1 = edge_a[e + 1];
        ushort4 u0 = *(const ushort4*)(y + (size_t)s0 * DIM + d);
        ushort4 u1 = *(const ushort4*)(y + (size_t)s1 * DIM + d);
        float g0 = fmaxf(bf2f(u0.x) + a0 * wv.x + bv.x, 0.0f) + GEN_EPS;
        float g1 = fmaxf(bf2f(u0.y) + a0 * wv.y + bv.y, 0.0f) + GEN_EPS;
        float g2 = fmaxf(bf2f(u0.z) + a0 * wv.z + bv.z, 0.0f) + GEN_EPS;
        float g3 = fmaxf(bf2f(u0.w) + a0 * wv.w + bv.w, 0.0f) + GEN_EPS;
        float h0 = fmaxf(bf2f(u1.x) + a1 * wv.x + bv.x, 0.0f) + GEN_EPS;
        float h1 = fmaxf(bf2f(u1.y) + a1 * wv.y + bv.y, 0.0f) + GEN_EPS;
        float h2 = fmaxf(bf2f(u1.z) + a1 * wv.z + bv.z, 0.0f) + GEN_EPS;
        float h3 = fmaxf(bf2f(u1.w) + a1 * wv.w + bv.w, 0.0f) + GEN_EPS;
        float w0 = exp2f(g0 * LOG2E), w1 = exp2f(g1 * LOG2E);
        float w2 = exp2f(g2 * LOG2E), w3 = exp2f(g3 * LOG2E);
        float x0 = exp2f(h0 * LOG2E), x1 = exp2f(h1 * LOG2E);
        float x2 = exp2f(h2 * LOG2E), x3 = exp2f(h3 * LOG2E);
        den0 += w0 + x0; ag0 += g0 * w0 + h0 * x0;
        den1 += w1 + x1; ag1 += g1 * w1 + h1 * x1;
        den2 += w2 + x2; ag2 += g2 * w2 + h2 * x2;
        den3 += w3 + x3; ag3 += g3 * w3 + h3 * x3;
    }
    if (e < hi) {
        int src = edge_src[e];
        float a = edge_a[e];
        ushort4 u = *(const ushort4*)(y + (size_t)src * DIM + d);
        float g0 = fmaxf(bf2f(u.x) + a * wv.x + bv.x, 0.0f) + GEN_EPS;
        float g1 = fmaxf(bf2f(u.y) + a * wv.y + bv.y, 0.0f) + GEN_EPS;
        float g2 = fmaxf(bf2f(u.z) + a * wv.z + bv.z, 0.0f) + GEN_EPS;
        float g3 = fmaxf(bf2f(u.w) + a * wv.w + bv.w, 0.0f) + GEN_EPS;
        float w0 = exp2f(g0 * LOG2E), w1 = exp2f(g1 * LOG2E);
        float w2 = exp2f(g2 * LOG2E), w3 = exp2f(g3 * LOG2E);
        den0 += w0; ag0 += g0 * w0;
        den1 += w1; ag1 += g1 * w1;
        den2 += w2; ag2 += g2 * w2;
        den3 += w3; ag3 += g3 * w3;
    }
    ushort4 ud = *(const ushort4*)(y + (size_t)dst * DIM + d);
    float o0 = ag0 / fmaxf(den0, 1e-16f) + bf2f(ud.x);
    float o1 = ag1 / fmaxf(den1, 1e-16f) + bf2f(ud.y);
    float o2 = ag2 / fmaxf(den2, 1e-16f) + bf2f(ud.z);
    float o3 = ag3 / fmaxf(den3, 1e-16f) + bf2f(ud.w);
    ushort4 o;
    o.x = f2bf(o0); o.y = f2bf(o1); o.z = f2bf(o2); o.w = f2bf(o3);
    *(ushort4*)(A + (size_t)dst * DIM + d) = o;
}

// ---------------- transpose + bf16 conv weights: WT[l][n][k] = bf16(W[l][k][n]) ----
__global__ void wt_kernel(const float* __restrict__ w, unsigned short* __restrict__ wt) {
    int idx = blockIdx.x * 256 + threadIdx.x;
    if (idx >= N_LAYERS * DIM * DIM) return;
    int l = idx >> 16;
    int rem = idx & 0xFFFF;
    int n = rem >> 8;
    int k = rem & 0xFF;
    wt[idx] = f2bf(w[(size_t)l * DIM * DIM + (size_t)k * DIM + n]);
}

// LDS-tiled transpose + hi/lo split: wth/wtl[n*K+k] from w[k*N+n]; K,N % 32 == 0
__global__ __launch_bounds__(256) void wt_ro_t_kernel(const float* __restrict__ w,
                                                      unsigned short* __restrict__ wth,
                                                      unsigned short* __restrict__ wtl,
                                                      int K, int N) {
    __shared__ float tile[32][33];
    int k0 = blockIdx.x * 32, n0 = blockIdx.y * 32;
    int tx = threadIdx.x & 31, ty = threadIdx.x >> 5;   // 8 rows per pass
    #pragma unroll
    for (int i = 0; i < 4; i++)
        tile[ty + 8 * i][tx] = w[(size_t)(k0 + ty + 8 * i) * N + n0 + tx];
    __syncthreads();
    #pragma unroll
    for (int i = 0; i < 4; i++) {
        int n = ty + 8 * i;
        float v = tile[tx][n];               // w[k0+tx][n0+n]
        unsigned short hh = f2bf(v);
        size_t idx = (size_t)(n0 + n) * K + k0 + tx;
        wth[idx] = hh;
        wtl[idx] = f2bf(v - bf2f(hh));
    }
}

// ---------------- MFMA conv GEMM + fused LN + fused pooling ----------------
// C^T swap. A fully LDS-staged; B k-slices double-buffered through LDS via
// global_load_lds. B swizzle mask is (n&3)<<4 — bits 4..5 only, a bijective
// permutation of the four 16B slots within each 64-byte row (rule #21).
__global__ __launch_bounds__(256) void mfma_gemm_kernel(const unsigned short* __restrict__ A,
                                                        const unsigned short* __restrict__ WT,
                                                        const float* __restrict__ bias,
                                                        const float* __restrict__ lnsc,
                                                        const float* __restrict__ lnbi,
                                                        const int* __restrict__ batch,
                                                        float* __restrict__ outs_f32,
                                                        int layer,
                                                        unsigned short* __restrict__ Cy,
                                                        int do_ln, int M) {
    __shared__ alignas(16) unsigned short Asmem[64 * 256];      // 32 KB
    __shared__ alignas(16) unsigned short Bsmem[2][256 * 32];   // 2 x 16 KB
    __shared__ float lsum[64][4];
    __shared__ float lsq[64][4];
    __shared__ int batch_lds[64];
    int lane = threadIdx.x & 63;
    int w = threadIdx.x >> 6;
    int m_base = blockIdx.x * 64;
    int n_base = w * 64;
    int frow = lane & 15;

    // ---- stage A-tile (64x256, 512B rows, mask bits 4..6 stay in-row) ----
    #pragma unroll
    for (int it = 0; it < 8; it++) {
        int C = (it * 4 + w) * 64 + lane;
        int row = C >> 5;
        int b0 = (C & 31) * 16;
        int kb = b0 ^ ((row & 7) << 4);
        int grow = m_base + row;
        if (grow >= M) grow = M - 1;
        const unsigned short* gsrc = A + (size_t)grow * DIM + (kb >> 1);
        unsigned short* ldst = Asmem + (size_t)(it * 4 + w) * 512;
        __builtin_amdgcn_global_load_lds((const GLOBAL_AS void*)gsrc,
                                         (LDS_AS void*)ldst, 16, 0, 0);
    }

    // ---- B k-slice staging: slice s = WT[n=0..255][k=s*32..+32), 64B rows ----
    auto stageB = [&](int buf, int s) {
        #pragma unroll
        for (int t = 0; t < 4; t++) {
            int C = (t * 4 + w) * 64 + lane;        // chunk id 0..1023
            int n = C >> 2;
            int b0 = (C & 3) * 16;                  // dest byte within 64B row
            int kb = b0 ^ ((n & 3) << 4);           // in-row bijection (bits 4..5)
            const unsigned short* gsrc = WT + (size_t)n * DIM + s * 32 + (kb >> 1);
            unsigned short* ldst = Bsmem[buf] + (size_t)(t * 4 + w) * 512;
            __builtin_amdgcn_global_load_lds((const GLOBAL_AS void*)gsrc,
                                             (LDS_AS void*)ldst, 16, 0, 0);
        }
    };
    stageB(0, 0);

    if (threadIdx.x < 64) {
        int gm = m_base + threadIdx.x;
        batch_lds[threadIdx.x] = batch[gm < M ? gm : (M - 1)];
    }

    __syncthreads();

    f32x4 acc[4][4];
    #pragma unroll
    for (int j = 0; j < 4; j++)
        #pragma unroll
        for (int i = 0; i < 4; i++) acc[j][i] = (f32x4){0.f, 0.f, 0.f, 0.f};

    #pragma unroll
    for (int s = 0; s < 8; s++) {
        int cur = s & 1;
        if (s < 7) stageB(cur ^ 1, s + 1);   // issue next slice before compute
        bf16x8 a[4], b[4];
        #pragma unroll
        for (int i = 0; i < 4; i++) {
            int r = i * 16 + frow;
            int bb = (s * 64 + (lane >> 4) * 16) ^ ((r & 7) << 4);
            a[i] = *(const bf16x8*)((const char*)Asmem + r * 512 + bb);
        }
        #pragma unroll
        for (int j = 0; j < 4; j++) {
            int n = n_base + j * 16 + frow;
            int kb = ((lane >> 4) * 16) ^ ((n & 3) << 4);
            b[j] = *(const bf16x8*)((const char*)Bsmem[cur] + n * 64 + kb);
        }
        #pragma unroll
        for (int j = 0; j < 4; j++)
            #pragma unroll
            for (int i = 0; i < 4; i++)
                acc[j][i] = __builtin_amdgcn_mfma_f32_16x16x32_bf16(b[j], a[i],
                                                                    acc[j][i], 0, 0, 0);
        if (s < 7) __syncthreads();
    }

    int mcol = lane & 15;          // m index within fragment
    int ng = (lane >> 4) * 4;      // n sub-offset (4 consecutive cols)

    float psum[4], psq[4];
    #pragma unroll
    for (int i = 0; i < 4; i++) { psum[i] = 0.f; psq[i] = 0.f; }

    // v = relu(acc + bias) kept in acc; LN row partials
    #pragma unroll
    for (int i = 0; i < 4; i++) {
        #pragma unroll
        for (int j = 0; j < 4; j++) {
            int n0 = n_base + j * 16 + ng;
            float4 bb = *(const float4*)(bias + n0);
            float v0 = fmaxf(acc[j][i][0] + bb.x, 0.0f);
            float v1 = fmaxf(acc[j][i][1] + bb.y, 0.0f);
            float v2 = fmaxf(acc[j][i][2] + bb.z, 0.0f);
            float v3 = fmaxf(acc[j][i][3] + bb.w, 0.0f);
            acc[j][i][0] = v0; acc[j][i][1] = v1; acc[j][i][2] = v2; acc[j][i][3] = v3;
            psum[i] += v0 + v1 + v2 + v3;
            psq[i] += v0 * v0 + v1 * v1 + v2 * v2 + v3 * v3;
        }
    }

    // ---- fused pooling: outs_f32[seg, layer*256 + col] += sum over rows ----
    float* outbase = outs_f32 + (size_t)layer * DIM;
    if (batch_lds[0] == batch_lds[63]) {
        int seg = batch_lds[0];
        #pragma unroll
        for (int j = 0; j < 4; j++) {
            float t0 = 0.f, t1 = 0.f, t2 = 0.f, t3 = 0.f;
            #pragma unroll
            for (int i = 0; i < 4; i++) {
                int gm = m_base + i * 16 + mcol;
                if (gm < M) {
                    t0 += acc[j][i][0]; t1 += acc[j][i][1];
                    t2 += acc[j][i][2]; t3 += acc[j][i][3];
                }
            }
            #pragma unroll
            for (int off = 1; off < 16; off <<= 1) {
                t0 += __shfl_xor(t0, off, 64);
                t1 += __shfl_xor(t1, off, 64);
                t2 += __shfl_xor(t2, off, 64);
                t3 += __shfl_xor(t3, off, 64);
            }
            if (mcol == 0) {
                float* op = outbase + (size_t)seg * (N_LAYERS * DIM) + n_base + j * 16 + ng;
                atomicAdd(op + 0, t0); atomicAdd(op + 1, t1);
                atomicAdd(op + 2, t2); atomicAdd(op + 3, t3);
            }
        }
    } else {
        #pragma unroll
        for (int i = 0; i < 4; i++) {
            int segA = batch_lds[i * 16];
            int segB = batch_lds[i * 16 + 15];
            int myseg = batch_lds[i * 16 + mcol];
            int gm = m_base + i * 16 + mcol;
            for (int seg = segA; seg <= segB; seg++) {
                bool mine = (myseg == seg) && (gm < M);
                #pragma unroll
                for (int j = 0; j < 4; j++) {
                    float t0 = mine ? acc[j][i][0] : 0.f;
                    float t1 = mine ? acc[j][i][1] : 0.f;
                    float t2 = mine ? acc[j][i][2] : 0.f;
                    float t3 = mine ? acc[j][i][3] : 0.f;
                    #pragma unroll
                    for (int off = 1; off < 16; off <<= 1) {
                        t0 += __shfl_xor(t0, off, 64);
                        t1 += __shfl_xor(t1, off, 64);
                        t2 += __shfl_xor(t2, off, 64);
                        t3 += __shfl_xor(t3, off, 64);
                    }
                    if (mcol == 0) {
                        float* op = outbase + (size_t)seg * (N_LAYERS * DIM) + n_base + j * 16 + ng;
                        atomicAdd(op + 0, t0); atomicAdd(op + 1, t1);
                        atomicAdd(op + 2, t2); atomicAdd(op + 3, t3);
                    }
                }
            }
        }
    }

    if (do_ln) {
        #pragma unroll
        for (int i = 0; i < 4; i++) {
            float s = psum[i], q = psq[i];
            s += __shfl_xor(s, 16, 64); q += __shfl_xor(q, 16, 64);
            s += __shfl_xor(s, 32, 64); q += __shfl_xor(q, 32, 64);
            if ((lane >> 4) == 0) {
                lsum[i * 16 + mcol][w] = s;
                lsq[i * 16 + mcol][w] = q;
            }
        }
        __syncthreads();
        #pragma unroll
        for (int i = 0; i < 4; i++) {
            int lr = i * 16 + mcol;
            float s = lsum[lr][0] + lsum[lr][1] + lsum[lr][2] + lsum[lr][3];
            float q = lsq[lr][0] + lsq[lr][1] + lsq[lr][2] + lsq[lr][3];
            float mu = s * (1.0f / DIM);
            float var = q * (1.0f / DIM) - mu * mu;
            float rs = rsqrtf(fmaxf(var, 0.0f) + LN_EPS);
            int gm = m_base + i * 16 + mcol;
            if (gm < M) {
                #pragma unroll
                for (int j = 0; j < 4; j++) {
                    int n0 = n_base + j * 16 + ng;
                    float4 sc = *(const float4*)(lnsc + n0);
                    float4 bi = *(const float4*)(lnbi + n0);
                    ushort4 o;
                    o.x = f2bf((acc[j][i][0] - mu) * rs * sc.x + bi.x);
                    o.y = f2bf((acc[j][i][1] - mu) * rs * sc.y + bi.y);
                    o.z = f2bf((acc[j][i][2] - mu) * rs * sc.z + bi.z);
                    o.w = f2bf((acc[j][i][3] - mu) * rs * sc.w + bi.w);
                    *(ushort4*)(Cy + (size_t)gm * DIM + n0) = o;
                }
            }
        }
    }
}

// ---------------- fp32 outs -> hi/lo bf16 ----------------
__global__ void conv_outs_kernel(const float* __restrict__ outs_f32,
                                 unsigned short* __restrict__ oh,
                                 unsigned short* __restrict__ ol) {
    int idx = blockIdx.x * 256 + threadIdx.x;
    if (idx >= N_BATCH * N_LAYERS * DIM) return;
    float v = outs_f32[idx];
    unsigned short hh = f2bf(v);
    oh[idx] = hh;
    ol[idx] = f2bf(v - bf2f(hh));
}

// ---------------- MFMA readout GEMM: block-per-16x16-tile, split-K over 4 waves ----
__global__ __launch_bounds__(256) void mfma_ro_kernel(const unsigned short* __restrict__ Ah,
                                                      const unsigned short* __restrict__ Al,
                                                      const unsigned short* __restrict__ WTh,
                                                      const unsigned short* __restrict__ WTl,
                                                      const float* __restrict__ bias,
                                                      unsigned short* __restrict__ Ch,
                                                      unsigned short* __restrict__ Cl,
                                                      int K, int Nc) {
    __shared__ float red[4][256];
    int lane = threadIdx.x & 63;
    int wave = threadIdx.x >> 6;
    int m0 = blockIdx.x * 16;
    int n0 = blockIdx.y * 16;
    int frow = lane & 15;
    int kp = (lane >> 4) * 8;
    int kc = K >> 2;
    int kbase = wave * kc;

    f32x4 acc = (f32x4){0.f, 0.f, 0.f, 0.f};
    const unsigned short* aph = Ah + (size_t)(m0 + frow) * K + kbase + kp;
    const unsigned short* apl = Al + (size_t)(m0 + frow) * K + kbase + kp;
    const unsigned short* bph = WTh + (size_t)(n0 + frow) * K + kbase + kp;
    const unsigned short* bpl = WTl + (size_t)(n0 + frow) * K + kbase + kp;
    #pragma unroll 4
    for (int k0 = 0; k0 < kc; k0 += 32) {
        bf16x8 ah = *(const bf16x8*)(aph + k0);
        bf16x8 al = *(const bf16x8*)(apl + k0);
        bf16x8 bh = *(const bf16x8*)(bph + k0);
        bf16x8 bl = *(const bf16x8*)(bpl + k0);
        acc = __builtin_amdgcn_mfma_f32_16x16x32_bf16(ah, bh, acc, 0, 0, 0);
        acc = __builtin_amdgcn_mfma_f32_16x16x32_bf16(ah, bl, acc, 0, 0, 0);
        acc = __builtin_amdgcn_mfma_f32_16x16x32_bf16(al, bh, acc, 0, 0, 0);
    }

    *(f32x4*)&red[wave][lane * 4] = acc;
    __syncthreads();
    if (wave == 0) {
        f32x4 a0 = *(const f32x4*)&red[0][lane * 4];
        f32x4 a1 = *(const f32x4*)&red[1][lane * 4];
        f32x4 a2 = *(const f32x4*)&red[2][lane * 4];
        f32x4 a3 = *(const f32x4*)&red[3][lane * 4];
        int ccol = lane & 15;
        int crow = (lane >> 4) * 4;
        float bb = bias[n0 + ccol];
        #pragma unroll
        for (int r = 0; r < 4; r++) {
            float v = a0[r] + a1[r] + a2[r] + a3[r] + bb;
            v = 0.5f * v * (1.0f + erff(v * 0.70710678118f));
            unsigned short hh = f2bf(v);
            size_t idx = (size_t)(m0 + crow + r) * Nc + n0 + ccol;
            Ch[idx] = hh;
            Cl[idx] = f2bf(v - bf2f(hh));
        }
    }
}

// ---------------- final: out[m] = (zh+zl)[m,:] . w3 + b3 ----------------
__global__ void final_kernel(const unsigned short* __restrict__ zh,
                             const unsigned short* __restrict__ zl,
                             const float* __restrict__ w,
                             const float* __restrict__ b, float* __restrict__ out) {
    int m = blockIdx.x * 64 + threadIdx.x;
    if (m >= N_BATCH) return;
    float s = 0.f;
    for (int k = 0; k < 192; k++)
        s += (bf2f(zh[(size_t)m * 192 + k]) + bf2f(zl[(size_t)m * 192 + k])) * w[k];
    out[m] = s + b[0];
}

__global__ void ws_sentinel_kernel(float* __restrict__ out) {
    int t = blockIdx.x * 256 + threadIdx.x;
    if (t < N_BATCH) out[t] = 1.0e6f;
}

extern "C" void kernel_launch(void* const* d_in, const int* in_sizes, int n_in,
                              void* d_out, int out_size, void* d_ws, size_t ws_size,
                              hipStream_t stream) {
    const int*   x        = (const int*)d_in[0];
    const int*   ei       = (const int*)d_in[1];
    const float* ea       = (const float*)d_in[2];
    const int*   batch    = (const int*)d_in[3];
    const float* node_emb = (const float*)d_in[4];
    const float* ln_scale = (const float*)d_in[5];
    const float* ln_bias  = (const float*)d_in[6];
    const float* wl_w     = (const float*)d_in[7];
    const float* wl_b     = (const float*)d_in[8];
    const float* conv_w   = (const float*)d_in[9];
    const float* conv_b   = (const float*)d_in[10];
    const float* ro_w0    = (const float*)d_in[11];
    const float* ro_b0    = (const float*)d_in[12];
    const float* ro_w1    = (const float*)d_in[13];
    const float* ro_b1    = (const float*)d_in[14];
    const float* ro_w2    = (const float*)d_in[15];
    const float* ro_b2    = (const float*)d_in[16];
    const float* ro_w3    = (const float*)d_in[17];
    const float* ro_b3    = (const float*)d_in[18];
    float* out = (float*)d_out;

    const size_t ND = (size_t)N_NODES * DIM;
    char* p = (char*)d_ws;
    unsigned short* y_buf = (unsigned short*)p;   p += ND * sizeof(unsigned short);
    unsigned short* A_buf = (unsigned short*)p;   p += ND * sizeof(unsigned short);
    float* outs_f32 = (float*)p;                  p += (size_t)N_BATCH * 1536 * sizeof(float);
    unsigned short* outs_h = (unsigned short*)p;  p += (size_t)N_BATCH * 1536 * sizeof(unsigned short);
    unsigned short* outs_l = (unsigned short*)p;  p += (size_t)N_BATCH * 1536 * sizeof(unsigned short);
    unsigned short* z1h = (unsigned short*)p;     p += (size_t)N_BATCH * 768 * sizeof(unsigned short);
    unsigned short* z1l = (unsigned short*)p;     p += (size_t)N_BATCH * 768 * sizeof(unsigned short);
    unsigned short* z2h = (unsigned short*)p;     p += (size_t)N_BATCH * 384 * sizeof(unsigned short);
    unsigned short* z2l = (unsigned short*)p;     p += (size_t)N_BATCH * 384 * sizeof(unsigned short);
    unsigned short* z3h = (unsigned short*)p;     p += (size_t)N_BATCH * 192 * sizeof(unsigned short);
    unsigned short* z3l = (unsigned short*)p;     p += (size_t)N_BATCH * 192 * sizeof(unsigned short);
    unsigned short* wt_buf = (unsigned short*)p;  p += (size_t)N_LAYERS * DIM * DIM * sizeof(unsigned short);
    unsigned short* wt0h = (unsigned short*)p;    p += (size_t)768 * 1536 * sizeof(unsigned short);
    unsigned short* wt0l = (unsigned short*)p;    p += (size_t)768 * 1536 * sizeof(unsigned short);
    unsigned short* wt1h = (unsigned short*)p;    p += (size_t)384 * 768 * sizeof(unsigned short);
    unsigned short* wt1l = (unsigned short*)p;    p += (size_t)384 * 768 * sizeof(unsigned short);
    unsigned short* wt2h = (unsigned short*)p;    p += (size_t)192 * 384 * sizeof(unsigned short);
    unsigned short* wt2l = (unsigned short*)p;    p += (size_t)192 * 384 * sizeof(unsigned short);
    float* edge_a = (float*)p;                    p += (size_t)N_EDGES * sizeof(float);
    int* deg = (int*)p;                           p += (size_t)N_NODES * sizeof(int);
    int* part = (int*)p;                          p += (size_t)NBLK * sizeof(int);
    int* ofs = (int*)p;                           p += (size_t)(N_NODES + 1) * sizeof(int);
    int* cursor = (int*)p;                        p += (size_t)N_NODES * sizeof(int);
    int* edge_src = (int*)p;                      p += (size_t)N_EDGES * sizeof(int);
    size_t need = (size_t)(p - (char*)d_ws);
    if (ws_size < need) {
        ws_sentinel_kernel<<<2, 256, 0, stream>>>(out);
        return;
    }

    int eb = (N_EDGES + 255) / 256;

    // ---- one-time prep ----
    hipMemsetAsync(deg, 0, N_NODES * sizeof(int), stream);
    hipMemsetAsync(outs_f32, 0, (size_t)N_BATCH * 1536 * sizeof(float), stream);
    hist_kernel<<<eb, 256, 0, stream>>>(ei, deg);
    scan1_kernel<<<NBLK, 256, 0, stream>>>(deg, part);
    scan2_kernel<<<1, 256, 0, stream>>>(part);
    scan3_kernel<<<NBLK, 256, 0, stream>>>(deg, part, ofs, cursor);
    scatter_kernel<<<eb, 256, 0, stream>>>(ei, ea, cursor, edge_src, edge_a);
    wt_kernel<<<(N_LAYERS * DIM * DIM + 255) / 256, 256, 0, stream>>>(conv_w, wt_buf);
    wt_ro_t_kernel<<<dim3(1536 / 32, 768 / 32), 256, 0, stream>>>(ro_w0, wt0h, wt0l, 1536, 768);
    wt_ro_t_kernel<<<dim3(768 / 32, 384 / 32), 256, 0, stream>>>(ro_w1, wt1h, wt1l, 768, 384);
    wt_ro_t_kernel<<<dim3(384 / 32, 192 / 32), 256, 0, stream>>>(ro_w2, wt2h, wt2l, 384, 192);

    int row_blocks = (N_NODES + 3) / 4;
    int gemm_blocks = (N_NODES + 63) / 64;

    // y0 = LN0(emb[x])  (h never materialized)
    embed_ln_kernel<<<row_blocks, 256, 0, stream>>>(x, node_emb, ln_scale, ln_bias, y_buf);

    for (int i = 0; i < N_LAYERS; i++) {
        agg_kernel<<<row_blocks, 256, 0, stream>>>(ofs, edge_src, edge_a, y_buf,
                                                   wl_w + i * DIM, wl_b + i * DIM, A_buf);
        int nl = (i + 1 < N_LAYERS) ? (i + 1) : i;
        mfma_gemm_kernel<<<gemm_blocks, 256, 0, stream>>>(A_buf, wt_buf + (size_t)i * DIM * DIM,
                                                          conv_b + i * DIM,
                                                          ln_scale + nl * DIM, ln_bias + nl * DIM,
                                                          batch, outs_f32, i, y_buf,
                                                          (i + 1 < N_LAYERS) ? 1 : 0, N_NODES);
    }

    // outs fp32 -> hi/lo bf16
    conv_outs_kernel<<<(N_BATCH * 1536 + 255) / 256, 256, 0, stream>>>(outs_f32, outs_h, outs_l);

    // readout MLP (hi/lo bf16 MFMA ~ fp32, split-K block-per-tile grids)
    mfma_ro_kernel<<<dim3(32, 48), 256, 0, stream>>>(outs_h, outs_l, wt0h, wt0l, ro_b0,
                                                     z1h, z1l, 1536, 768);
    mfma_ro_kernel<<<dim3(32, 24), 256, 0, stream>>>(z1h, z1l, wt1h, wt1l, ro_b1,
                                                     z2h, z2l, 768, 384);
    mfma_ro_kernel<<<dim3(32, 12), 256, 0, stream>>>(z2h, z2l, wt2h, wt2l, ro_b2,
                                                     z3h, z3l, 384, 192);
    final_kernel<<<(N_BATCH + 63) / 64, 64, 0, stream>>>(z3h, z3l, ro_w3, ro_b3, out);
}